// Round 14
// baseline (3537.369 us; speedup 1.0000x reference)
//
#include <hip/hip_runtime.h>

#define N_NODES 50000
#define N_EDGES 800000
#define N_ITERS 7
#define NPAD 50048
#define NT16 (N_EDGES / 16)   // 50000 16-edge tiles
#define TOTW 2048             // 512 blocks x 4 waves
#define TPW ((NT16 + TOTW - 1) / TOTW)   // 25 tiles per wave

typedef __attribute__((ext_vector_type(8))) short short8;
typedef __attribute__((ext_vector_type(4))) float f32x4;

#define AROW 104   // wave-private relay row: 96 bf16 + 8 pad
#define XROW 296   // X row: 288 bf16 + 8 pad

static __device__ __forceinline__ unsigned short f2bf(float f) {
    unsigned int u = __float_as_uint(f);
    unsigned int r = (u + 0x7fffu + ((u >> 16) & 1u)) >> 16;
    return (unsigned short)r;
}
static __device__ __forceinline__ float bf2f(unsigned short u) {
    return __uint_as_float(((unsigned int)u) << 16);
}
// pack two f32 -> 2x bf16 (RNE), lo in bits [15:0]
static __device__ __forceinline__ unsigned cvt_pk_bf16(float lo, float hi) {
    unsigned r;
    asm("v_cvt_pk_bf16_f32 %0, %1, %2" : "=v"(r) : "v"(lo), "v"(hi));
    return r;
}
static __device__ __forceinline__ float fast_tanh(float x) {
    float xc = fminf(fmaxf(x, -15.f), 15.f);
    float t = __expf(2.f * xc);
    return (t - 1.f) / (t + 1.f);
}
// row_ror:1 (0x121): lane i <- lane (i-1) mod 16, so col0 receives col15.
static __device__ __forceinline__ float ror_prev(float x) {
    return __int_as_float(__builtin_amdgcn_update_dpp(0, __float_as_int(x), 0x121, 0xf, 0xf, true));
}

// one segmented-scan step over the 16-lane row group (row_shr:CTRL&15, bound_ctrl=1)
template <int CTRL>
static __device__ __forceinline__ void seg_step(float (&s)[24], unsigned& fl) {
    unsigned fv = (unsigned)__builtin_amdgcn_update_dpp(0, (int)fl, CTRL, 0xf, 0xf, true);
    float g = fl ? 0.f : 1.f;
#pragma unroll
    for (int q = 0; q < 24; q++) {
        int sv = __builtin_amdgcn_update_dpp(0, __float_as_int(s[q]), CTRL, 0xf, 0xf, true);
        s[q] += __int_as_float(sv) * g;
    }
    fl |= fv;
}

// ---------------------------------------------------------------------------
// Wbig [256][288]: rows = r,z gates; cols = [W_ih[:, :64] | W_ih[:,64:]@W3 | W_hh]
__global__ __launch_bounds__(256) void k_build_wbig(const float* __restrict__ W_ih,
                                                    const float* __restrict__ W3,
                                                    const float* __restrict__ W_hh,
                                                    float* __restrict__ Wbig) {
    int idx = blockIdx.x * 256 + threadIdx.x;
    if (idx >= 256 * 288) return;
    int g = idx / 288, k = idx - g * 288;
    float v;
    if (k < 64) v = W_ih[g * 192 + k];
    else if (k < 160) {
        int kk = k - 64; float s = 0.f;
        for (int j = 0; j < 128; j++) s += W_ih[g * 192 + 64 + j] * W3[j * 96 + kk];
        v = s;
    } else v = W_hh[g * 128 + (k - 160)];
    Wbig[idx] = v;
}

// Wni [128][160]: n-gate input part (W_ih rows 256..383, with W3 fold)
__global__ __launch_bounds__(256) void k_build_wni(const float* __restrict__ W_ih,
                                                   const float* __restrict__ W3,
                                                   float* __restrict__ Wni) {
    int idx = blockIdx.x * 256 + threadIdx.x;
    if (idx >= 128 * 160) return;
    int g = idx / 160, k = idx - g * 160;
    int gg = 256 + g;
    float v;
    if (k < 64) v = W_ih[gg * 192 + k];
    else {
        int kk = k - 64; float s = 0.f;
        for (int j = 0; j < 128; j++) s += W_ih[gg * 192 + 64 + j] * W3[j * 96 + kk];
        v = s;
    }
    Wni[idx] = v;
}

__global__ __launch_bounds__(256) void k_vb3(const float* __restrict__ W_ih,
                                             const float* __restrict__ b3,
                                             float* __restrict__ vb3) {
    int g = blockIdx.x * 256 + threadIdx.x;
    if (g >= 384) return;
    float s = 0.f;
    for (int j = 0; j < 128; j++) s += W_ih[g * 192 + 64 + j] * b3[j];
    vb3[g] = s;
}

__global__ __launch_bounds__(256) void k_bsum(const float* __restrict__ b_ih,
                                              const float* __restrict__ b_hh,
                                              float* __restrict__ bsum) {
    int d = blockIdx.x * 256 + threadIdx.x;
    if (d >= 384) return;
    bsum[d] = b_ih[d] + (d < 256 ? b_hh[d] : 0.f);
}

// ---------------------------------------------------------------------------
// Pack: src fp32 (ld), element (row0+j, k) -> A-frags [Mt][KT][64][8]
__global__ __launch_bounds__(256) void k_pack2(const float* __restrict__ src,
                                               unsigned short* __restrict__ out,
                                               int Mt, int KT, int ld, int row0) {
    int idx = blockIdx.x * 256 + threadIdx.x;
    if (idx >= Mt * KT * 512) return;
    int jj = idx & 7;
    int l  = (idx >> 3) & 63;
    int tile = idx >> 9;
    int kt = tile % KT;
    int mt = tile / KT;
    int j = row0 + mt * 16 + (l & 15);
    int k = kt * 32 + (l >> 4) * 8 + jj;
    out[idx] = f2bf(src[(size_t)j * ld + k]);
}

// ---------------------------------------------------------------------------
// CSR build (once; ids fixed across iterations)
__global__ __launch_bounds__(256) void k_hist(const int* __restrict__ dst,
                                              int* __restrict__ counts) {
    int e = blockIdx.x * 256 + threadIdx.x;
    if (e < N_EDGES) atomicAdd(&counts[dst[e]], 1);
}

__global__ __launch_bounds__(1024) void k_scan(const int* __restrict__ counts,
                                               int* __restrict__ row_off) {
    __shared__ int sh[1024];
    int t = threadIdx.x;
    const int STR = 49;
    int base = t * STR;
    int s = 0;
    for (int i = 0; i < STR; i++) {
        int n = base + i;
        if (n < N_NODES) s += counts[n];
    }
    sh[t] = s;
    __syncthreads();
    for (int off = 1; off < 1024; off <<= 1) {
        int v = (t >= off) ? sh[t - off] : 0;
        __syncthreads();
        sh[t] += v;
        __syncthreads();
    }
    int run = (t == 0) ? 0 : sh[t - 1];
    for (int i = 0; i < STR; i++) {
        int n = base + i;
        if (n < N_NODES) { row_off[n] = run; run += counts[n]; }
    }
    if (t == 1023) row_off[N_NODES] = run;
}

__global__ __launch_bounds__(256) void k_permute(const int* __restrict__ src,
                                                 const int* __restrict__ dst,
                                                 const int* __restrict__ row_off,
                                                 int* __restrict__ cursor,
                                                 int* __restrict__ perm_src,
                                                 int* __restrict__ perm_dst) {
    int e = blockIdx.x * 256 + threadIdx.x;
    if (e >= N_EDGES) return;
    int d = dst[e];
    int pos = row_off[d] + atomicAdd(&cursor[d], 1);
    perm_src[pos] = src[e];
    perm_dst[pos] = d;
}

// ---------------------------------------------------------------------------
// Fused edge MLP + aggregation. 4 waves/block, W1 LDS-cached, W2 frags read
// from global (L1-resident, 18KB) -> LDS = 62464B so 2 blocks/CU co-reside
// (R11's 80896B blocked 2nd block; R12/R13 8-wave blocks spilled at 128 VGPR).
// Register carry chain; plain float4 stores for interior nodes; atomics only
// at wave-range boundaries. DPP segmented scan; 3-stage pipeline; setprio.
__global__ __launch_bounds__(256, 2) void k_edge_fused(
    const unsigned short* __restrict__ hbf,   // [N][128] bf16
    const int* __restrict__ perm_src, const int* __restrict__ perm_dst,
    const short8* __restrict__ W1Ag,          // [6*8*64] frags
    const short8* __restrict__ W2Ag,          // [6*3*64] frags (read via L1)
    const float* __restrict__ b1,
    const float* __restrict__ b2,
    float* __restrict__ r2agg)                // [NPAD][96]
{
    __shared__ __attribute__((aligned(16))) short8 W1s[6 * 8 * 64];      // 49152 B
    __shared__ __attribute__((aligned(16))) unsigned short relay[4][16][AROW]; // 13312 B

    int t = threadIdx.x;
    int w = t >> 6, l = t & 63;
    int col = l & 15, krow = l >> 4;

    for (int i = t; i < 6 * 8 * 64; i += 256) W1s[i] = W1Ag[i];
    __syncthreads();   // only barrier in the kernel

    int wtid = blockIdx.x * 4 + w;
    int tlo = wtid * TPW;
    int thi = tlo + TPW; if (thi > NT16) thi = NT16;
    if (tlo >= thi) return;

    auto mkmask = [&](int did) -> unsigned {
        int dp = __shfl_up(did, 1);
        return (unsigned)__ballot((col == 0) || (did != dp)) & 0xFFFFu;
    };
    auto gather = [&](int sid, int did, short8* fr) {
        const unsigned short* sr = hbf + (size_t)sid * 128 + krow * 8;
        const unsigned short* dr = hbf + (size_t)did * 128 + krow * 8;
#pragma unroll
        for (int kt = 0; kt < 4; kt++) fr[kt]     = *(const short8*)(sr + kt * 32);
#pragma unroll
        for (int kt = 0; kt < 4; kt++) fr[4 + kt] = *(const short8*)(dr + kt * 32);
    };

    float carry[24];
#pragma unroll
    for (int q = 0; q < 24; q++) carry[q] = 0.f;
    bool head = true;   // carry chain touches the wave's first edge

    auto process = [&](unsigned m16, int did, const short8* fr,
                       bool continuing, bool lastTile) {
        // ---- L1: c1 = W1 * m^T ----
        f32x4 c1[6] = {};
        __builtin_amdgcn_s_setprio(1);
#pragma unroll
        for (int kt = 0; kt < 8; kt++) {
#pragma unroll
            for (int mt = 0; mt < 6; mt++)
                c1[mt] = __builtin_amdgcn_mfma_f32_16x16x32_bf16(W1s[(mt * 8 + kt) * 64 + l], fr[kt], c1[mt], 0, 0, 0);
        }
        __builtin_amdgcn_s_setprio(0);
        // ---- a1 epilogue -> wave-private LDS relay ----
#pragma unroll
        for (int mt = 0; mt < 6; mt++) {
#pragma unroll
            for (int r = 0; r < 4; r += 2) {
                int j0 = mt * 16 + krow * 4 + r;
                float v0 = fmaxf(c1[mt][r]     + b1[j0],     0.f);
                float v1 = fmaxf(c1[mt][r + 1] + b1[j0 + 1], 0.f);
                *(unsigned int*)(&relay[w][col][j0]) = cvt_pk_bf16(v0, v1);
            }
        }
        // ---- L2 (A-frags from global; 18KB working set stays in L1) ----
        f32x4 c2[6] = {};
        __builtin_amdgcn_s_setprio(1);
#pragma unroll
        for (int kt = 0; kt < 3; kt++) {
            short8 b = *(const short8*)(&relay[w][col][kt * 32 + krow * 8]);
#pragma unroll
            for (int mt = 0; mt < 6; mt++)
                c2[mt] = __builtin_amdgcn_mfma_f32_16x16x32_bf16(W2Ag[(mt * 3 + kt) * 64 + l], b, c2[mt], 0, 0, 0);
        }
        __builtin_amdgcn_s_setprio(0);
        // ---- msg (bias+relu) in registers; inject carry at col0 ----
        float s[24];
#pragma unroll
        for (int mt = 0; mt < 6; mt++)
#pragma unroll
            for (int r = 0; r < 4; r++) {
                int j = mt * 16 + krow * 4 + r;
                float v = fmaxf(c2[mt][r] + b2[j], 0.f);
                s[mt * 4 + r] = v + ((col == 0) ? carry[mt * 4 + r] : 0.f);
            }
        // ---- segmented inclusive scan over col ----
        unsigned fl = (m16 >> col) & 1u;
        seg_step<0x111>(s, fl);
        seg_step<0x112>(s, fl);
        seg_step<0x114>(s, fl);
        seg_step<0x118>(s, fl);
        // ---- emission ----
        bool is_end = (col == 15) || ((m16 >> (col + 1)) & 1u);
        if (is_end && !((col == 15) && continuing)) {
            unsigned lowmask = (2u << col) - 1u;
            bool first_seg = (__popc(m16 & lowmask) == 1);
            bool use_atomic = (first_seg && head) || ((col == 15) && lastTile);
            float* base = r2agg + (size_t)did * 96 + krow * 4;
            if (use_atomic) {
#pragma unroll
                for (int mt = 0; mt < 6; mt++)
#pragma unroll
                    for (int r = 0; r < 4; r++)
                        atomicAdd(base + mt * 16 + r, s[mt * 4 + r]);
            } else {
#pragma unroll
                for (int mt = 0; mt < 6; mt++)
                    *(float4*)(base + mt * 16) = make_float4(s[mt * 4], s[mt * 4 + 1],
                                                             s[mt * 4 + 2], s[mt * 4 + 3]);
            }
        }
        // ---- carry update (wave-uniform) ----
        if (continuing) {
            head = head && (m16 == 1u);
#pragma unroll
            for (int q = 0; q < 24; q++) carry[q] = ror_prev(s[q]);
        } else {
            head = false;
#pragma unroll
            for (int q = 0; q < 24; q++) carry[q] = 0.f;
        }
    };

    // ---- 3-stage pipelined contiguous-tile loop ----
    int tA = tlo;
    unsigned mA, mB;
    int sidA = 0, didA = 0, sidB = 0, didB = 0, sidC = 0, didC = 0;
    short8 frA[8], frB[8];

    { int e = tA * 16 + col; sidA = perm_src[e]; didA = perm_dst[e]; }
    bool hasB = (tA + 1 < thi);
    if (hasB) { int e = (tA + 1) * 16 + col; sidB = perm_src[e]; didB = perm_dst[e]; }
    mA = mkmask(didA);
    gather(sidA, didA, frA);

    for (;;) {
        bool hasC = (tA + 2 < thi);
        if (hasC) { int e = (tA + 2) * 16 + col; sidC = perm_src[e]; didC = perm_dst[e]; }
        if (hasB) { mB = mkmask(didB); gather(sidB, didB, frB); }
        bool continuing = hasB && (__shfl(didA, 15) == __shfl(didB, 0));
        process(mA, didA, frA, continuing, !hasB);
        if (!hasB) break;
        mA = mB; didA = didB;
#pragma unroll
        for (int i = 0; i < 8; i++) frA[i] = frB[i];
        sidB = sidC; didB = didC;
        hasB = hasC;
        tA++;
    }
}

// ---------------------------------------------------------------------------
// Node phase: 4 waves x 64 shared nodes; wave w owns d-range [32w,32w+32)
// of all gates (and out rows [16w,16w+16)). Weights read once per wave with
// x4 B-frag reuse. 3 barriers, no weight staging.
__global__ __launch_bounds__(256) void k_node_mfma(
    const float* __restrict__ inp,      // [N][64]
    const float* __restrict__ r2agg,    // [NPAD][96]
    const int* __restrict__ row_off,    // [N+1]
    float* __restrict__ h,              // [N][128] fp32 in/out
    unsigned short* __restrict__ hbf,   // [N][128] bf16 in/out
    const short8* __restrict__ WbigA,   // [16][9] tiles
    const short8* __restrict__ WniA,    // [8][5]
    const short8* __restrict__ WnhA,    // [8][4]
    const short8* __restrict__ WoutA,   // [4][4]
    const float* __restrict__ vb3,
    const float* __restrict__ bsum,
    const float* __restrict__ b_hh,
    const float* __restrict__ b_out,
    float* __restrict__ out, int iter)
{
    __shared__ __attribute__((aligned(16))) unsigned short X[4][16][XROW]; // 37888 B
    __shared__ float degs[64];
    int t = threadIdx.x;
    int w = t >> 6, l = t & 63;
    int nb = blockIdx.x * 64;
    int col = l & 15, krow = l >> 4;

    // ---- stage X = [inp(64) | r2(96) | h(128)] bf16 + degs ----
    for (int idx = t; idx < 64 * 32; idx += 256) {
        int i = idx >> 5, kk = (idx & 31) << 1;
        int n = nb + i;
        float2 v = make_float2(0.f, 0.f);
        if (n < N_NODES) v = *(const float2*)(inp + (size_t)n * 64 + kk);
        *(unsigned int*)(&X[i >> 4][i & 15][kk]) = cvt_pk_bf16(v.x, v.y);
    }
    for (int idx = t; idx < 64 * 48; idx += 256) {      // r2 node-major pairs
        int i = (int)((unsigned)idx / 48u), kp = idx - i * 48;
        int n = nb + i;
        float2 v = make_float2(0.f, 0.f);
        if (n < N_NODES) v = *(const float2*)(r2agg + (size_t)n * 96 + kp * 2);
        *(unsigned int*)(&X[i >> 4][i & 15][64 + kp * 2]) = cvt_pk_bf16(v.x, v.y);
    }
    for (int idx = t; idx < 64 * 16; idx += 256) {
        int i = idx >> 4, c = idx & 15;
        int n = nb + i;
        uint4 v = make_uint4(0, 0, 0, 0);
        if (n < N_NODES) v = ((const uint4*)(hbf + (size_t)n * 128))[c];
        *(uint4*)(&X[i >> 4][i & 15][160 + c * 8]) = v;
    }
    if (t < 64) {
        int n = nb + t;
        degs[t] = (n < N_NODES) ? (float)(row_off[n + 1] - row_off[n]) : 0.f;
    }
    __syncthreads();

    // ---- GEMMs: wave w computes d in [32w, 32w+32) ----
    int mts[4] = {2 * w, 2 * w + 1, 8 + 2 * w, 9 + 2 * w};   // r lo/hi, z lo/hi
    f32x4 cg[4][4] = {};
#pragma unroll 3
    for (int kt = 0; kt < 9; kt++) {
        short8 b[4];
#pragma unroll
        for (int bf = 0; bf < 4; bf++) b[bf] = *(const short8*)(&X[bf][col][kt * 32 + krow * 8]);
#pragma unroll
        for (int mi = 0; mi < 4; mi++) {
            short8 a = WbigA[(mts[mi] * 9 + kt) * 64 + l];
#pragma unroll
            for (int bf = 0; bf < 4; bf++)
                cg[mi][bf] = __builtin_amdgcn_mfma_f32_16x16x32_bf16(a, b[bf], cg[mi][bf], 0, 0, 0);
        }
    }
    f32x4 ci[2][4] = {};
#pragma unroll
    for (int kt = 0; kt < 5; kt++) {
        short8 b[4];
#pragma unroll
        for (int bf = 0; bf < 4; bf++) b[bf] = *(const short8*)(&X[bf][col][kt * 32 + krow * 8]);
#pragma unroll
        for (int mi = 0; mi < 2; mi++) {
            short8 a = WniA[((2 * w + mi) * 5 + kt) * 64 + l];
#pragma unroll
            for (int bf = 0; bf < 4; bf++)
                ci[mi][bf] = __builtin_amdgcn_mfma_f32_16x16x32_bf16(a, b[bf], ci[mi][bf], 0, 0, 0);
        }
    }
    f32x4 ch[2][4] = {};
#pragma unroll
    for (int kt = 0; kt < 4; kt++) {
        short8 b[4];
#pragma unroll
        for (int bf = 0; bf < 4; bf++) b[bf] = *(const short8*)(&X[bf][col][160 + kt * 32 + krow * 8]);
#pragma unroll
        for (int mi = 0; mi < 2; mi++) {
            short8 a = WnhA[((2 * w + mi) * 4 + kt) * 64 + l];
#pragma unroll
            for (int bf = 0; bf < 4; bf++)
                ch[mi][bf] = __builtin_amdgcn_mfma_f32_16x16x32_bf16(a, b[bf], ch[mi][bf], 0, 0, 0);
        }
    }
    __syncthreads();   // all reads of old-h in X complete

    // ---- GRU epilogue: wave w writes d-range [32w,32w+32) for all 64 nodes ----
#pragma unroll
    for (int mi = 0; mi < 2; mi++) {
        int d0 = w * 32 + mi * 16 + krow * 4;
        float4 bsr = *(const float4*)(bsum + d0);
        float4 bsz = *(const float4*)(bsum + 128 + d0);
        float4 bsn = *(const float4*)(bsum + 256 + d0);
        float4 vbr = *(const float4*)(vb3 + d0);
        float4 vbz = *(const float4*)(vb3 + 128 + d0);
        float4 vbn = *(const float4*)(vb3 + 256 + d0);
        float4 bhn = *(const float4*)(b_hh + 256 + d0);
        float bsrv[4] = {bsr.x, bsr.y, bsr.z, bsr.w};
        float bszv[4] = {bsz.x, bsz.y, bsz.z, bsz.w};
        float bsnv[4] = {bsn.x, bsn.y, bsn.z, bsn.w};
        float vbrv[4] = {vbr.x, vbr.y, vbr.z, vbr.w};
        float vbzv[4] = {vbz.x, vbz.y, vbz.z, vbz.w};
        float vbnv[4] = {vbn.x, vbn.y, vbn.z, vbn.w};
        float bhnv[4] = {bhn.x, bhn.y, bhn.z, bhn.w};
#pragma unroll
        for (int bf = 0; bf < 4; bf++) {
            int n = nb + bf * 16 + col;
            bool valid = (n < N_NODES);
            float deg = degs[bf * 16 + col];
            float4 ho = make_float4(0.f, 0.f, 0.f, 0.f);
            if (valid) ho = *(const float4*)(h + (size_t)n * 128 + d0);
            float hov[4] = {ho.x, ho.y, ho.z, ho.w};
            float hv[4];
#pragma unroll
            for (int r = 0; r < 4; r++) {
                float rp = cg[mi][bf][r]     + bsrv[r] + deg * vbrv[r];
                float zp = cg[2 + mi][bf][r] + bszv[r] + deg * vbzv[r];
                float ip = ci[mi][bf][r]     + bsnv[r] + deg * vbnv[r];
                float hp = ch[mi][bf][r]     + bhnv[r];
                float rg = 1.f / (1.f + __expf(-rp));
                float zg = 1.f / (1.f + __expf(-zp));
                float ng = fast_tanh(ip + rg * hp);
                hv[r] = (1.f - zg) * ng + zg * hov[r];
            }
            if (valid)
                *(float4*)(h + (size_t)n * 128 + d0) = make_float4(hv[0], hv[1], hv[2], hv[3]);
            *(unsigned int*)(&X[bf][col][160 + d0])     = cvt_pk_bf16(hv[0], hv[1]);
            *(unsigned int*)(&X[bf][col][160 + d0 + 2]) = cvt_pk_bf16(hv[2], hv[3]);
        }
    }
    __syncthreads();   // h_new complete in X

    // ---- out projection: wave w computes rows [16w,16w+16) ----
    f32x4 co[4] = {};
#pragma unroll
    for (int kt = 0; kt < 4; kt++) {
        short8 a = WoutA[(w * 4 + kt) * 64 + l];
#pragma unroll
        for (int bf = 0; bf < 4; bf++) {
            short8 b = *(const short8*)(&X[bf][col][160 + kt * 32 + krow * 8]);
            co[bf] = __builtin_amdgcn_mfma_f32_16x16x32_bf16(a, b, co[bf], 0, 0, 0);
        }
    }
    {
        int o0 = w * 16 + krow * 4;
        float4 bo = *(const float4*)(b_out + o0);
#pragma unroll
        for (int bf = 0; bf < 4; bf++) {
            int n = nb + bf * 16 + col;
            if (n < N_NODES) {
                float* op = out + (size_t)iter * N_NODES * 64 + (size_t)n * 64 + o0;
                *(float4*)op = make_float4(co[bf][0] + bo.x, co[bf][1] + bo.y,
                                           co[bf][2] + bo.z, co[bf][3] + bo.w);
            }
        }
    }

    // ---- hbf writeback ----
    for (int idx = t; idx < 64 * 16; idx += 256) {
        int i = idx >> 4, c = idx & 15;
        int n2 = nb + i;
        if (n2 < N_NODES)
            ((uint4*)(hbf + (size_t)n2 * 128))[c] = *(const uint4*)(&X[i >> 4][i & 15][160 + c * 8]);
    }
}

// ---------------------------------------------------------------------------
extern "C" void kernel_launch(void* const* d_in, const int* in_sizes, int n_in,
                              void* d_out, int out_size, void* d_ws, size_t ws_size,
                              hipStream_t stream)
{
    const float* inp   = (const float*)d_in[0];
    const int*   src   = (const int*)d_in[1];
    const int*   dst   = (const int*)d_in[2];
    const float* W1    = (const float*)d_in[3];
    const float* b1    = (const float*)d_in[4];
    const float* W2    = (const float*)d_in[5];
    const float* b2    = (const float*)d_in[6];
    const float* W3    = (const float*)d_in[7];
    const float* b3    = (const float*)d_in[8];
    const float* W_ih  = (const float*)d_in[9];
    const float* W_hh  = (const float*)d_in[10];
    const float* b_ih  = (const float*)d_in[11];
    const float* b_hh  = (const float*)d_in[12];
    const float* W_out = (const float*)d_in[13];
    const float* b_out = (const float*)d_in[14];
    float* out = (float*)d_out;

    char* ws = (char*)d_ws;
    size_t off = 0;
    auto alloc = [&](size_t bytes) -> void* {
        void* p = ws + off;
        off += (bytes + 255) & ~(size_t)255;
        return p;
    };
    float* h       = (float*)alloc((size_t)N_NODES * 128 * 4);
    unsigned short* hbf = (unsigned short*)alloc((size_t)N_NODES * 128 * 2);
    float* r2agg   = (float*)alloc((size_t)NPAD * 96 * 4);
    float* Wbig    = (float*)alloc((size_t)256 * 288 * 4);
    float* Wni     = (float*)alloc((size_t)128 * 160 * 4);
    float* vb3     = (float*)alloc((size_t)384 * 4);
    float* bsum    = (float*)alloc((size_t)384 * 4);
    unsigned short* W1A   = (unsigned short*)alloc((size_t)6 * 8 * 512 * 2);
    unsigned short* W2A   = (unsigned short*)alloc((size_t)6 * 3 * 512 * 2);
    unsigned short* WbigA = (unsigned short*)alloc((size_t)16 * 9 * 512 * 2);
    unsigned short* WniA  = (unsigned short*)alloc((size_t)8 * 5 * 512 * 2);
    unsigned short* WnhA  = (unsigned short*)alloc((size_t)8 * 4 * 512 * 2);
    unsigned short* WoutA = (unsigned short*)alloc((size_t)4 * 4 * 512 * 2);
    int*   counts  = (int*)alloc((size_t)N_NODES * 4);
    int*   cursor  = (int*)alloc((size_t)N_NODES * 4);
    int*   row_off = (int*)alloc((size_t)(N_NODES + 1) * 4);
    int*   perm_src= (int*)alloc((size_t)N_EDGES * 4);
    int*   perm_dst= (int*)alloc((size_t)N_EDGES * 4);

    // ---- one-time preprocessing ----
    hipMemsetAsync(h, 0, (size_t)N_NODES * 128 * 4, stream);
    hipMemsetAsync(hbf, 0, (size_t)N_NODES * 128 * 2, stream);
    hipMemsetAsync(counts, 0, (size_t)N_NODES * 4, stream);
    hipMemsetAsync(cursor, 0, (size_t)N_NODES * 4, stream);

    k_build_wbig<<<(256 * 288 + 255) / 256, 256, 0, stream>>>(W_ih, W3, W_hh, Wbig);
    k_build_wni<<<(128 * 160 + 255) / 256, 256, 0, stream>>>(W_ih, W3, Wni);
    k_vb3<<<2, 256, 0, stream>>>(W_ih, b3, vb3);
    k_bsum<<<2, 256, 0, stream>>>(b_ih, b_hh, bsum);

    k_pack2<<<(6 * 8 * 512 + 255) / 256, 256, 0, stream>>>(W1, W1A, 6, 8, 256, 0);
    k_pack2<<<(6 * 3 * 512 + 255) / 256, 256, 0, stream>>>(W2, W2A, 6, 3, 96, 0);
    k_pack2<<<(16 * 9 * 512 + 255) / 256, 256, 0, stream>>>(Wbig, WbigA, 16, 9, 288, 0);
    k_pack2<<<(8 * 5 * 512 + 255) / 256, 256, 0, stream>>>(Wni, WniA, 8, 5, 160, 0);
    k_pack2<<<(8 * 4 * 512 + 255) / 256, 256, 0, stream>>>(W_hh, WnhA, 8, 4, 128, 256);
    k_pack2<<<(4 * 4 * 512 + 255) / 256, 256, 0, stream>>>(W_out, WoutA, 4, 4, 128, 0);

    k_hist<<<(N_EDGES + 255) / 256, 256, 0, stream>>>(dst, counts);
    k_scan<<<1, 1024, 0, stream>>>(counts, row_off);
    k_permute<<<(N_EDGES + 255) / 256, 256, 0, stream>>>(src, dst, row_off, cursor,
                                                         perm_src, perm_dst);

    // ---- iterations ----
    for (int it = 0; it < N_ITERS; ++it) {
        hipMemsetAsync(r2agg, 0, (size_t)NPAD * 96 * 4, stream);
        k_edge_fused<<<512, 256, 0, stream>>>(hbf, perm_src, perm_dst,
                                              (const short8*)W1A, (const short8*)W2A,
                                              b1, b2, r2agg);
        k_node_mfma<<<(N_NODES + 63) / 64, 256, 0, stream>>>(inp, r2agg, row_off, h, hbf,
                                                     (const short8*)WbigA, (const short8*)WniA,
                                                     (const short8*)WnhA, (const short8*)WoutA,
                                                     vb3, bsum, b_hh, b_out, out, it);
    }
}

// Round 15
// 2317.303 us; speedup vs baseline: 1.5265x; 1.5265x over previous
//
#include <hip/hip_runtime.h>

#define N_NODES 50000
#define N_EDGES 800000
#define N_ITERS 7
#define NPAD 50048
#define NT16 (N_EDGES / 16)   // 50000 16-edge tiles
#define TOTW 2048             // 512 blocks x 4 waves
#define TPW ((NT16 + TOTW - 1) / TOTW)   // 25 tiles per wave

typedef __attribute__((ext_vector_type(8))) short short8;
typedef __attribute__((ext_vector_type(4))) float f32x4;

#define AROW 104   // wave-private relay row: 96 bf16 + 8 pad
#define XROW 296   // X row: 288 bf16 + 8 pad

static __device__ __forceinline__ unsigned short f2bf(float f) {
    unsigned int u = __float_as_uint(f);
    unsigned int r = (u + 0x7fffu + ((u >> 16) & 1u)) >> 16;
    return (unsigned short)r;
}
static __device__ __forceinline__ float bf2f(unsigned short u) {
    return __uint_as_float(((unsigned int)u) << 16);
}
// pack two f32 -> 2x bf16 (RNE), lo in bits [15:0]
static __device__ __forceinline__ unsigned cvt_pk_bf16(float lo, float hi) {
    unsigned r;
    asm("v_cvt_pk_bf16_f32 %0, %1, %2" : "=v"(r) : "v"(lo), "v"(hi));
    return r;
}
static __device__ __forceinline__ float fast_tanh(float x) {
    float xc = fminf(fmaxf(x, -15.f), 15.f);
    float t = __expf(2.f * xc);
    return (t - 1.f) / (t + 1.f);
}
// row_ror:1 (0x121): lane i <- lane (i-1) mod 16, so col0 receives col15.
static __device__ __forceinline__ float ror_prev(float x) {
    return __int_as_float(__builtin_amdgcn_update_dpp(0, __float_as_int(x), 0x121, 0xf, 0xf, true));
}

// one segmented-scan step over the 16-lane row group (row_shr:CTRL&15, bound_ctrl=1)
template <int CTRL>
static __device__ __forceinline__ void seg_step(float (&s)[24], unsigned& fl) {
    unsigned fv = (unsigned)__builtin_amdgcn_update_dpp(0, (int)fl, CTRL, 0xf, 0xf, true);
    float g = fl ? 0.f : 1.f;
#pragma unroll
    for (int q = 0; q < 24; q++) {
        int sv = __builtin_amdgcn_update_dpp(0, __float_as_int(s[q]), CTRL, 0xf, 0xf, true);
        s[q] += __int_as_float(sv) * g;
    }
    fl |= fv;
}

// ---------------------------------------------------------------------------
// Wbig [256][288]: rows = r,z gates; cols = [W_ih[:, :64] | W_ih[:,64:]@W3 | W_hh]
__global__ __launch_bounds__(256) void k_build_wbig(const float* __restrict__ W_ih,
                                                    const float* __restrict__ W3,
                                                    const float* __restrict__ W_hh,
                                                    float* __restrict__ Wbig) {
    int idx = blockIdx.x * 256 + threadIdx.x;
    if (idx >= 256 * 288) return;
    int g = idx / 288, k = idx - g * 288;
    float v;
    if (k < 64) v = W_ih[g * 192 + k];
    else if (k < 160) {
        int kk = k - 64; float s = 0.f;
        for (int j = 0; j < 128; j++) s += W_ih[g * 192 + 64 + j] * W3[j * 96 + kk];
        v = s;
    } else v = W_hh[g * 128 + (k - 160)];
    Wbig[idx] = v;
}

// Wni [128][160]: n-gate input part (W_ih rows 256..383, with W3 fold)
__global__ __launch_bounds__(256) void k_build_wni(const float* __restrict__ W_ih,
                                                   const float* __restrict__ W3,
                                                   float* __restrict__ Wni) {
    int idx = blockIdx.x * 256 + threadIdx.x;
    if (idx >= 128 * 160) return;
    int g = idx / 160, k = idx - g * 160;
    int gg = 256 + g;
    float v;
    if (k < 64) v = W_ih[gg * 192 + k];
    else {
        int kk = k - 64; float s = 0.f;
        for (int j = 0; j < 128; j++) s += W_ih[gg * 192 + 64 + j] * W3[j * 96 + kk];
        v = s;
    }
    Wni[idx] = v;
}

__global__ __launch_bounds__(256) void k_vb3(const float* __restrict__ W_ih,
                                             const float* __restrict__ b3,
                                             float* __restrict__ vb3) {
    int g = blockIdx.x * 256 + threadIdx.x;
    if (g >= 384) return;
    float s = 0.f;
    for (int j = 0; j < 128; j++) s += W_ih[g * 192 + 64 + j] * b3[j];
    vb3[g] = s;
}

__global__ __launch_bounds__(256) void k_bsum(const float* __restrict__ b_ih,
                                              const float* __restrict__ b_hh,
                                              float* __restrict__ bsum) {
    int d = blockIdx.x * 256 + threadIdx.x;
    if (d >= 384) return;
    bsum[d] = b_ih[d] + (d < 256 ? b_hh[d] : 0.f);
}

// ---------------------------------------------------------------------------
// Pack: src fp32 (ld), element (row0+j, k) -> A-frags [Mt][KT][64][8]
__global__ __launch_bounds__(256) void k_pack2(const float* __restrict__ src,
                                               unsigned short* __restrict__ out,
                                               int Mt, int KT, int ld, int row0) {
    int idx = blockIdx.x * 256 + threadIdx.x;
    if (idx >= Mt * KT * 512) return;
    int jj = idx & 7;
    int l  = (idx >> 3) & 63;
    int tile = idx >> 9;
    int kt = tile % KT;
    int mt = tile / KT;
    int j = row0 + mt * 16 + (l & 15);
    int k = kt * 32 + (l >> 4) * 8 + jj;
    out[idx] = f2bf(src[(size_t)j * ld + k]);
}

// ---------------------------------------------------------------------------
// CSR build (once; ids fixed across iterations)
__global__ __launch_bounds__(256) void k_hist(const int* __restrict__ dst,
                                              int* __restrict__ counts) {
    int e = blockIdx.x * 256 + threadIdx.x;
    if (e < N_EDGES) atomicAdd(&counts[dst[e]], 1);
}

__global__ __launch_bounds__(1024) void k_scan(const int* __restrict__ counts,
                                               int* __restrict__ row_off) {
    __shared__ int sh[1024];
    int t = threadIdx.x;
    const int STR = 49;
    int base = t * STR;
    int s = 0;
    for (int i = 0; i < STR; i++) {
        int n = base + i;
        if (n < N_NODES) s += counts[n];
    }
    sh[t] = s;
    __syncthreads();
    for (int off = 1; off < 1024; off <<= 1) {
        int v = (t >= off) ? sh[t - off] : 0;
        __syncthreads();
        sh[t] += v;
        __syncthreads();
    }
    int run = (t == 0) ? 0 : sh[t - 1];
    for (int i = 0; i < STR; i++) {
        int n = base + i;
        if (n < N_NODES) { row_off[n] = run; run += counts[n]; }
    }
    if (t == 1023) row_off[N_NODES] = run;
}

__global__ __launch_bounds__(256) void k_permute(const int* __restrict__ src,
                                                 const int* __restrict__ dst,
                                                 const int* __restrict__ row_off,
                                                 int* __restrict__ cursor,
                                                 int* __restrict__ perm_src,
                                                 int* __restrict__ perm_dst) {
    int e = blockIdx.x * 256 + threadIdx.x;
    if (e >= N_EDGES) return;
    int d = dst[e];
    int pos = row_off[d] + atomicAdd(&cursor[d], 1);
    perm_src[pos] = src[e];
    perm_dst[pos] = d;
}

// ---------------------------------------------------------------------------
// Fused edge MLP + aggregation. 4 waves/block, W1 LDS-cached, W2 frags read
// from global (L1-resident, 18KB) -> LDS = 62464B so 2 blocks/CU co-reside.
// NO second launch_bounds arg: R12/R13/R14 all proved any value >=2 forces a
// 128-VGPR cap and spills (FETCH 630-786MB). Plain (256) gives ~236 VGPR;
// 2 waves/SIMD fit naturally (2x236=472 <= 512-VGPR pool).
// Register carry chain; plain float4 stores for interior nodes; atomics only
// at wave-range boundaries. DPP segmented scan; 3-stage pipeline; setprio.
__global__ __launch_bounds__(256) void k_edge_fused(
    const unsigned short* __restrict__ hbf,   // [N][128] bf16
    const int* __restrict__ perm_src, const int* __restrict__ perm_dst,
    const short8* __restrict__ W1Ag,          // [6*8*64] frags
    const short8* __restrict__ W2Ag,          // [6*3*64] frags (read via L1)
    const float* __restrict__ b1,
    const float* __restrict__ b2,
    float* __restrict__ r2agg)                // [NPAD][96]
{
    __shared__ __attribute__((aligned(16))) short8 W1s[6 * 8 * 64];      // 49152 B
    __shared__ __attribute__((aligned(16))) unsigned short relay[4][16][AROW]; // 13312 B

    int t = threadIdx.x;
    int w = t >> 6, l = t & 63;
    int col = l & 15, krow = l >> 4;

    for (int i = t; i < 6 * 8 * 64; i += 256) W1s[i] = W1Ag[i];
    __syncthreads();   // only barrier in the kernel

    int wtid = blockIdx.x * 4 + w;
    int tlo = wtid * TPW;
    int thi = tlo + TPW; if (thi > NT16) thi = NT16;
    if (tlo >= thi) return;

    auto mkmask = [&](int did) -> unsigned {
        int dp = __shfl_up(did, 1);
        return (unsigned)__ballot((col == 0) || (did != dp)) & 0xFFFFu;
    };
    auto gather = [&](int sid, int did, short8* fr) {
        const unsigned short* sr = hbf + (size_t)sid * 128 + krow * 8;
        const unsigned short* dr = hbf + (size_t)did * 128 + krow * 8;
#pragma unroll
        for (int kt = 0; kt < 4; kt++) fr[kt]     = *(const short8*)(sr + kt * 32);
#pragma unroll
        for (int kt = 0; kt < 4; kt++) fr[4 + kt] = *(const short8*)(dr + kt * 32);
    };

    float carry[24];
#pragma unroll
    for (int q = 0; q < 24; q++) carry[q] = 0.f;
    bool head = true;   // carry chain touches the wave's first edge

    auto process = [&](unsigned m16, int did, const short8* fr,
                       bool continuing, bool lastTile) {
        // ---- L1: c1 = W1 * m^T ----
        f32x4 c1[6] = {};
        __builtin_amdgcn_s_setprio(1);
#pragma unroll
        for (int kt = 0; kt < 8; kt++) {
#pragma unroll
            for (int mt = 0; mt < 6; mt++)
                c1[mt] = __builtin_amdgcn_mfma_f32_16x16x32_bf16(W1s[(mt * 8 + kt) * 64 + l], fr[kt], c1[mt], 0, 0, 0);
        }
        __builtin_amdgcn_s_setprio(0);
        // ---- a1 epilogue -> wave-private LDS relay ----
#pragma unroll
        for (int mt = 0; mt < 6; mt++) {
#pragma unroll
            for (int r = 0; r < 4; r += 2) {
                int j0 = mt * 16 + krow * 4 + r;
                float v0 = fmaxf(c1[mt][r]     + b1[j0],     0.f);
                float v1 = fmaxf(c1[mt][r + 1] + b1[j0 + 1], 0.f);
                *(unsigned int*)(&relay[w][col][j0]) = cvt_pk_bf16(v0, v1);
            }
        }
        // ---- L2 (A-frags from global; 18KB working set stays in L1) ----
        f32x4 c2[6] = {};
        __builtin_amdgcn_s_setprio(1);
#pragma unroll
        for (int kt = 0; kt < 3; kt++) {
            short8 b = *(const short8*)(&relay[w][col][kt * 32 + krow * 8]);
#pragma unroll
            for (int mt = 0; mt < 6; mt++)
                c2[mt] = __builtin_amdgcn_mfma_f32_16x16x32_bf16(W2Ag[(mt * 3 + kt) * 64 + l], b, c2[mt], 0, 0, 0);
        }
        __builtin_amdgcn_s_setprio(0);
        // ---- msg (bias+relu) in registers; inject carry at col0 ----
        float s[24];
#pragma unroll
        for (int mt = 0; mt < 6; mt++)
#pragma unroll
            for (int r = 0; r < 4; r++) {
                int j = mt * 16 + krow * 4 + r;
                float v = fmaxf(c2[mt][r] + b2[j], 0.f);
                s[mt * 4 + r] = v + ((col == 0) ? carry[mt * 4 + r] : 0.f);
            }
        // ---- segmented inclusive scan over col ----
        unsigned fl = (m16 >> col) & 1u;
        seg_step<0x111>(s, fl);
        seg_step<0x112>(s, fl);
        seg_step<0x114>(s, fl);
        seg_step<0x118>(s, fl);
        // ---- emission ----
        bool is_end = (col == 15) || ((m16 >> (col + 1)) & 1u);
        if (is_end && !((col == 15) && continuing)) {
            unsigned lowmask = (2u << col) - 1u;
            bool first_seg = (__popc(m16 & lowmask) == 1);
            bool use_atomic = (first_seg && head) || ((col == 15) && lastTile);
            float* base = r2agg + (size_t)did * 96 + krow * 4;
            if (use_atomic) {
#pragma unroll
                for (int mt = 0; mt < 6; mt++)
#pragma unroll
                    for (int r = 0; r < 4; r++)
                        atomicAdd(base + mt * 16 + r, s[mt * 4 + r]);
            } else {
#pragma unroll
                for (int mt = 0; mt < 6; mt++)
                    *(float4*)(base + mt * 16) = make_float4(s[mt * 4], s[mt * 4 + 1],
                                                             s[mt * 4 + 2], s[mt * 4 + 3]);
            }
        }
        // ---- carry update (wave-uniform) ----
        if (continuing) {
            head = head && (m16 == 1u);
#pragma unroll
            for (int q = 0; q < 24; q++) carry[q] = ror_prev(s[q]);
        } else {
            head = false;
#pragma unroll
            for (int q = 0; q < 24; q++) carry[q] = 0.f;
        }
    };

    // ---- 3-stage pipelined contiguous-tile loop ----
    int tA = tlo;
    unsigned mA, mB;
    int sidA = 0, didA = 0, sidB = 0, didB = 0, sidC = 0, didC = 0;
    short8 frA[8], frB[8];

    { int e = tA * 16 + col; sidA = perm_src[e]; didA = perm_dst[e]; }
    bool hasB = (tA + 1 < thi);
    if (hasB) { int e = (tA + 1) * 16 + col; sidB = perm_src[e]; didB = perm_dst[e]; }
    mA = mkmask(didA);
    gather(sidA, didA, frA);

    for (;;) {
        bool hasC = (tA + 2 < thi);
        if (hasC) { int e = (tA + 2) * 16 + col; sidC = perm_src[e]; didC = perm_dst[e]; }
        if (hasB) { mB = mkmask(didB); gather(sidB, didB, frB); }
        bool continuing = hasB && (__shfl(didA, 15) == __shfl(didB, 0));
        process(mA, didA, frA, continuing, !hasB);
        if (!hasB) break;
        mA = mB; didA = didB;
#pragma unroll
        for (int i = 0; i < 8; i++) frA[i] = frB[i];
        sidB = sidC; didB = didC;
        hasB = hasC;
        tA++;
    }
}

// ---------------------------------------------------------------------------
// Node phase: 4 waves x 64 shared nodes; wave w owns d-range [32w,32w+32)
// of all gates (and out rows [16w,16w+16)). Weights read once per wave with
// x4 B-frag reuse. 3 barriers, no weight staging.
__global__ __launch_bounds__(256) void k_node_mfma(
    const float* __restrict__ inp,      // [N][64]
    const float* __restrict__ r2agg,    // [NPAD][96]
    const int* __restrict__ row_off,    // [N+1]
    float* __restrict__ h,              // [N][128] fp32 in/out
    unsigned short* __restrict__ hbf,   // [N][128] bf16 in/out
    const short8* __restrict__ WbigA,   // [16][9] tiles
    const short8* __restrict__ WniA,    // [8][5]
    const short8* __restrict__ WnhA,    // [8][4]
    const short8* __restrict__ WoutA,   // [4][4]
    const float* __restrict__ vb3,
    const float* __restrict__ bsum,
    const float* __restrict__ b_hh,
    const float* __restrict__ b_out,
    float* __restrict__ out, int iter)
{
    __shared__ __attribute__((aligned(16))) unsigned short X[4][16][XROW]; // 37888 B
    __shared__ float degs[64];
    int t = threadIdx.x;
    int w = t >> 6, l = t & 63;
    int nb = blockIdx.x * 64;
    int col = l & 15, krow = l >> 4;

    // ---- stage X = [inp(64) | r2(96) | h(128)] bf16 + degs ----
    for (int idx = t; idx < 64 * 32; idx += 256) {
        int i = idx >> 5, kk = (idx & 31) << 1;
        int n = nb + i;
        float2 v = make_float2(0.f, 0.f);
        if (n < N_NODES) v = *(const float2*)(inp + (size_t)n * 64 + kk);
        *(unsigned int*)(&X[i >> 4][i & 15][kk]) = cvt_pk_bf16(v.x, v.y);
    }
    for (int idx = t; idx < 64 * 48; idx += 256) {      // r2 node-major pairs
        int i = (int)((unsigned)idx / 48u), kp = idx - i * 48;
        int n = nb + i;
        float2 v = make_float2(0.f, 0.f);
        if (n < N_NODES) v = *(const float2*)(r2agg + (size_t)n * 96 + kp * 2);
        *(unsigned int*)(&X[i >> 4][i & 15][64 + kp * 2]) = cvt_pk_bf16(v.x, v.y);
    }
    for (int idx = t; idx < 64 * 16; idx += 256) {
        int i = idx >> 4, c = idx & 15;
        int n = nb + i;
        uint4 v = make_uint4(0, 0, 0, 0);
        if (n < N_NODES) v = ((const uint4*)(hbf + (size_t)n * 128))[c];
        *(uint4*)(&X[i >> 4][i & 15][160 + c * 8]) = v;
    }
    if (t < 64) {
        int n = nb + t;
        degs[t] = (n < N_NODES) ? (float)(row_off[n + 1] - row_off[n]) : 0.f;
    }
    __syncthreads();

    // ---- GEMMs: wave w computes d in [32w, 32w+32) ----
    int mts[4] = {2 * w, 2 * w + 1, 8 + 2 * w, 9 + 2 * w};   // r lo/hi, z lo/hi
    f32x4 cg[4][4] = {};
#pragma unroll 3
    for (int kt = 0; kt < 9; kt++) {
        short8 b[4];
#pragma unroll
        for (int bf = 0; bf < 4; bf++) b[bf] = *(const short8*)(&X[bf][col][kt * 32 + krow * 8]);
#pragma unroll
        for (int mi = 0; mi < 4; mi++) {
            short8 a = WbigA[(mts[mi] * 9 + kt) * 64 + l];
#pragma unroll
            for (int bf = 0; bf < 4; bf++)
                cg[mi][bf] = __builtin_amdgcn_mfma_f32_16x16x32_bf16(a, b[bf], cg[mi][bf], 0, 0, 0);
        }
    }
    f32x4 ci[2][4] = {};
#pragma unroll
    for (int kt = 0; kt < 5; kt++) {
        short8 b[4];
#pragma unroll
        for (int bf = 0; bf < 4; bf++) b[bf] = *(const short8*)(&X[bf][col][kt * 32 + krow * 8]);
#pragma unroll
        for (int mi = 0; mi < 2; mi++) {
            short8 a = WniA[((2 * w + mi) * 5 + kt) * 64 + l];
#pragma unroll
            for (int bf = 0; bf < 4; bf++)
                ci[mi][bf] = __builtin_amdgcn_mfma_f32_16x16x32_bf16(a, b[bf], ci[mi][bf], 0, 0, 0);
        }
    }
    f32x4 ch[2][4] = {};
#pragma unroll
    for (int kt = 0; kt < 4; kt++) {
        short8 b[4];
#pragma unroll
        for (int bf = 0; bf < 4; bf++) b[bf] = *(const short8*)(&X[bf][col][160 + kt * 32 + krow * 8]);
#pragma unroll
        for (int mi = 0; mi < 2; mi++) {
            short8 a = WnhA[((2 * w + mi) * 4 + kt) * 64 + l];
#pragma unroll
            for (int bf = 0; bf < 4; bf++)
                ch[mi][bf] = __builtin_amdgcn_mfma_f32_16x16x32_bf16(a, b[bf], ch[mi][bf], 0, 0, 0);
        }
    }
    __syncthreads();   // all reads of old-h in X complete

    // ---- GRU epilogue: wave w writes d-range [32w,32w+32) for all 64 nodes ----
#pragma unroll
    for (int mi = 0; mi < 2; mi++) {
        int d0 = w * 32 + mi * 16 + krow * 4;
        float4 bsr = *(const float4*)(bsum + d0);
        float4 bsz = *(const float4*)(bsum + 128 + d0);
        float4 bsn = *(const float4*)(bsum + 256 + d0);
        float4 vbr = *(const float4*)(vb3 + d0);
        float4 vbz = *(const float4*)(vb3 + 128 + d0);
        float4 vbn = *(const float4*)(vb3 + 256 + d0);
        float4 bhn = *(const float4*)(b_hh + 256 + d0);
        float bsrv[4] = {bsr.x, bsr.y, bsr.z, bsr.w};
        float bszv[4] = {bsz.x, bsz.y, bsz.z, bsz.w};
        float bsnv[4] = {bsn.x, bsn.y, bsn.z, bsn.w};
        float vbrv[4] = {vbr.x, vbr.y, vbr.z, vbr.w};
        float vbzv[4] = {vbz.x, vbz.y, vbz.z, vbz.w};
        float vbnv[4] = {vbn.x, vbn.y, vbn.z, vbn.w};
        float bhnv[4] = {bhn.x, bhn.y, bhn.z, bhn.w};
#pragma unroll
        for (int bf = 0; bf < 4; bf++) {
            int n = nb + bf * 16 + col;
            bool valid = (n < N_NODES);
            float deg = degs[bf * 16 + col];
            float4 ho = make_float4(0.f, 0.f, 0.f, 0.f);
            if (valid) ho = *(const float4*)(h + (size_t)n * 128 + d0);
            float hov[4] = {ho.x, ho.y, ho.z, ho.w};
            float hv[4];
#pragma unroll
            for (int r = 0; r < 4; r++) {
                float rp = cg[mi][bf][r]     + bsrv[r] + deg * vbrv[r];
                float zp = cg[2 + mi][bf][r] + bszv[r] + deg * vbzv[r];
                float ip = ci[mi][bf][r]     + bsnv[r] + deg * vbnv[r];
                float hp = ch[mi][bf][r]     + bhnv[r];
                float rg = 1.f / (1.f + __expf(-rp));
                float zg = 1.f / (1.f + __expf(-zp));
                float ng = fast_tanh(ip + rg * hp);
                hv[r] = (1.f - zg) * ng + zg * hov[r];
            }
            if (valid)
                *(float4*)(h + (size_t)n * 128 + d0) = make_float4(hv[0], hv[1], hv[2], hv[3]);
            *(unsigned int*)(&X[bf][col][160 + d0])     = cvt_pk_bf16(hv[0], hv[1]);
            *(unsigned int*)(&X[bf][col][160 + d0 + 2]) = cvt_pk_bf16(hv[2], hv[3]);
        }
    }
    __syncthreads();   // h_new complete in X

    // ---- out projection: wave w computes rows [16w,16w+16) ----
    f32x4 co[4] = {};
#pragma unroll
    for (int kt = 0; kt < 4; kt++) {
        short8 a = WoutA[(w * 4 + kt) * 64 + l];
#pragma unroll
        for (int bf = 0; bf < 4; bf++) {
            short8 b = *(const short8*)(&X[bf][col][160 + kt * 32 + krow * 8]);
            co[bf] = __builtin_amdgcn_mfma_f32_16x16x32_bf16(a, b, co[bf], 0, 0, 0);
        }
    }
    {
        int o0 = w * 16 + krow * 4;
        float4 bo = *(const float4*)(b_out + o0);
#pragma unroll
        for (int bf = 0; bf < 4; bf++) {
            int n = nb + bf * 16 + col;
            if (n < N_NODES) {
                float* op = out + (size_t)iter * N_NODES * 64 + (size_t)n * 64 + o0;
                *(float4*)op = make_float4(co[bf][0] + bo.x, co[bf][1] + bo.y,
                                           co[bf][2] + bo.z, co[bf][3] + bo.w);
            }
        }
    }

    // ---- hbf writeback ----
    for (int idx = t; idx < 64 * 16; idx += 256) {
        int i = idx >> 4, c = idx & 15;
        int n2 = nb + i;
        if (n2 < N_NODES)
            ((uint4*)(hbf + (size_t)n2 * 128))[c] = *(const uint4*)(&X[i >> 4][i & 15][160 + c * 8]);
    }
}

// ---------------------------------------------------------------------------
extern "C" void kernel_launch(void* const* d_in, const int* in_sizes, int n_in,
                              void* d_out, int out_size, void* d_ws, size_t ws_size,
                              hipStream_t stream)
{
    const float* inp   = (const float*)d_in[0];
    const int*   src   = (const int*)d_in[1];
    const int*   dst   = (const int*)d_in[2];
    const float* W1    = (const float*)d_in[3];
    const float* b1    = (const float*)d_in[4];
    const float* W2    = (const float*)d_in[5];
    const float* b2    = (const float*)d_in[6];
    const float* W3    = (const float*)d_in[7];
    const float* b3    = (const float*)d_in[8];
    const float* W_ih  = (const float*)d_in[9];
    const float* W_hh  = (const float*)d_in[10];
    const float* b_ih  = (const float*)d_in[11];
    const float* b_hh  = (const float*)d_in[12];
    const float* W_out = (const float*)d_in[13];
    const float* b_out = (const float*)d_in[14];
    float* out = (float*)d_out;

    char* ws = (char*)d_ws;
    size_t off = 0;
    auto alloc = [&](size_t bytes) -> void* {
        void* p = ws + off;
        off += (bytes + 255) & ~(size_t)255;
        return p;
    };
    float* h       = (float*)alloc((size_t)N_NODES * 128 * 4);
    unsigned short* hbf = (unsigned short*)alloc((size_t)N_NODES * 128 * 2);
    float* r2agg   = (float*)alloc((size_t)NPAD * 96 * 4);
    float* Wbig    = (float*)alloc((size_t)256 * 288 * 4);
    float* Wni     = (float*)alloc((size_t)128 * 160 * 4);
    float* vb3     = (float*)alloc((size_t)384 * 4);
    float* bsum    = (float*)alloc((size_t)384 * 4);
    unsigned short* W1A   = (unsigned short*)alloc((size_t)6 * 8 * 512 * 2);
    unsigned short* W2A   = (unsigned short*)alloc((size_t)6 * 3 * 512 * 2);
    unsigned short* WbigA = (unsigned short*)alloc((size_t)16 * 9 * 512 * 2);
    unsigned short* WniA  = (unsigned short*)alloc((size_t)8 * 5 * 512 * 2);
    unsigned short* WnhA  = (unsigned short*)alloc((size_t)8 * 4 * 512 * 2);
    unsigned short* WoutA = (unsigned short*)alloc((size_t)4 * 4 * 512 * 2);
    int*   counts  = (int*)alloc((size_t)N_NODES * 4);
    int*   cursor  = (int*)alloc((size_t)N_NODES * 4);
    int*   row_off = (int*)alloc((size_t)(N_NODES + 1) * 4);
    int*   perm_src= (int*)alloc((size_t)N_EDGES * 4);
    int*   perm_dst= (int*)alloc((size_t)N_EDGES * 4);

    // ---- one-time preprocessing ----
    hipMemsetAsync(h, 0, (size_t)N_NODES * 128 * 4, stream);
    hipMemsetAsync(hbf, 0, (size_t)N_NODES * 128 * 2, stream);
    hipMemsetAsync(counts, 0, (size_t)N_NODES * 4, stream);
    hipMemsetAsync(cursor, 0, (size_t)N_NODES * 4, stream);

    k_build_wbig<<<(256 * 288 + 255) / 256, 256, 0, stream>>>(W_ih, W3, W_hh, Wbig);
    k_build_wni<<<(128 * 160 + 255) / 256, 256, 0, stream>>>(W_ih, W3, Wni);
    k_vb3<<<2, 256, 0, stream>>>(W_ih, b3, vb3);
    k_bsum<<<2, 256, 0, stream>>>(b_ih, b_hh, bsum);

    k_pack2<<<(6 * 8 * 512 + 255) / 256, 256, 0, stream>>>(W1, W1A, 6, 8, 256, 0);
    k_pack2<<<(6 * 3 * 512 + 255) / 256, 256, 0, stream>>>(W2, W2A, 6, 3, 96, 0);
    k_pack2<<<(16 * 9 * 512 + 255) / 256, 256, 0, stream>>>(Wbig, WbigA, 16, 9, 288, 0);
    k_pack2<<<(8 * 5 * 512 + 255) / 256, 256, 0, stream>>>(Wni, WniA, 8, 5, 160, 0);
    k_pack2<<<(8 * 4 * 512 + 255) / 256, 256, 0, stream>>>(W_hh, WnhA, 8, 4, 128, 256);
    k_pack2<<<(4 * 4 * 512 + 255) / 256, 256, 0, stream>>>(W_out, WoutA, 4, 4, 128, 0);

    k_hist<<<(N_EDGES + 255) / 256, 256, 0, stream>>>(dst, counts);
    k_scan<<<1, 1024, 0, stream>>>(counts, row_off);
    k_permute<<<(N_EDGES + 255) / 256, 256, 0, stream>>>(src, dst, row_off, cursor,
                                                         perm_src, perm_dst);

    // ---- iterations ----
    for (int it = 0; it < N_ITERS; ++it) {
        hipMemsetAsync(r2agg, 0, (size_t)NPAD * 96 * 4, stream);
        k_edge_fused<<<512, 256, 0, stream>>>(hbf, perm_src, perm_dst,
                                              (const short8*)W1A, (const short8*)W2A,
                                              b1, b2, r2agg);
        k_node_mfma<<<(N_NODES + 63) / 64, 256, 0, stream>>>(inp, r2agg, row_off, h, hbf,
                                                     (const short8*)WbigA, (const short8*)WniA,
                                                     (const short8*)WnhA, (const short8*)WoutA,
                                                     vb3, bsum, b_hh, b_out, out, it);
    }
}

// Round 16
// 1971.572 us; speedup vs baseline: 1.7942x; 1.1754x over previous
//
#include <hip/hip_runtime.h>

#define N_NODES 50000
#define N_EDGES 800000
#define N_ITERS 7
#define NPAD 50048
#define NT16 (N_EDGES / 16)   // 50000 16-edge tiles
#define TOTW 2048             // 512 blocks x 4 waves
#define TPW ((NT16 + TOTW - 1) / TOTW)   // 25 tiles per wave

typedef __attribute__((ext_vector_type(8))) short short8;
typedef __attribute__((ext_vector_type(4))) float f32x4;

#define AROW 104   // wave-private relay row: 96 bf16 + 8 pad
#define XROW 296   // X row: 288 bf16 + 8 pad

static __device__ __forceinline__ unsigned short f2bf(float f) {
    unsigned int u = __float_as_uint(f);
    unsigned int r = (u + 0x7fffu + ((u >> 16) & 1u)) >> 16;
    return (unsigned short)r;
}
static __device__ __forceinline__ float bf2f(unsigned short u) {
    return __uint_as_float(((unsigned int)u) << 16);
}
// pack two f32 -> 2x bf16 (RNE), lo in bits [15:0]
static __device__ __forceinline__ unsigned cvt_pk_bf16(float lo, float hi) {
    unsigned r;
    asm("v_cvt_pk_bf16_f32 %0, %1, %2" : "=v"(r) : "v"(lo), "v"(hi));
    return r;
}
static __device__ __forceinline__ float fast_tanh(float x) {
    float xc = fminf(fmaxf(x, -15.f), 15.f);
    float t = __expf(2.f * xc);
    return (t - 1.f) / (t + 1.f);
}
// row_ror:1 (0x121): lane i <- lane (i-1) mod 16, so col0 receives col15.
static __device__ __forceinline__ float ror_prev(float x) {
    return __int_as_float(__builtin_amdgcn_update_dpp(0, __float_as_int(x), 0x121, 0xf, 0xf, true));
}

// one segmented-scan step over the 16-lane row group (row_shr:CTRL&15, bound_ctrl=1)
template <int CTRL>
static __device__ __forceinline__ void seg_step(float (&s)[24], unsigned& fl) {
    unsigned fv = (unsigned)__builtin_amdgcn_update_dpp(0, (int)fl, CTRL, 0xf, 0xf, true);
    float g = fl ? 0.f : 1.f;
#pragma unroll
    for (int q = 0; q < 24; q++) {
        int sv = __builtin_amdgcn_update_dpp(0, __float_as_int(s[q]), CTRL, 0xf, 0xf, true);
        s[q] += __int_as_float(sv) * g;
    }
    fl |= fv;
}

// ---------------------------------------------------------------------------
// Wbig [256][288]: rows = r,z gates; cols = [W_ih[:, :64] | W_ih[:,64:]@W3 | W_hh]
__global__ __launch_bounds__(256) void k_build_wbig(const float* __restrict__ W_ih,
                                                    const float* __restrict__ W3,
                                                    const float* __restrict__ W_hh,
                                                    float* __restrict__ Wbig) {
    int idx = blockIdx.x * 256 + threadIdx.x;
    if (idx >= 256 * 288) return;
    int g = idx / 288, k = idx - g * 288;
    float v;
    if (k < 64) v = W_ih[g * 192 + k];
    else if (k < 160) {
        int kk = k - 64; float s = 0.f;
        for (int j = 0; j < 128; j++) s += W_ih[g * 192 + 64 + j] * W3[j * 96 + kk];
        v = s;
    } else v = W_hh[g * 128 + (k - 160)];
    Wbig[idx] = v;
}

// Wni [128][160]: n-gate input part (W_ih rows 256..383, with W3 fold)
__global__ __launch_bounds__(256) void k_build_wni(const float* __restrict__ W_ih,
                                                   const float* __restrict__ W3,
                                                   float* __restrict__ Wni) {
    int idx = blockIdx.x * 256 + threadIdx.x;
    if (idx >= 128 * 160) return;
    int g = idx / 160, k = idx - g * 160;
    int gg = 256 + g;
    float v;
    if (k < 64) v = W_ih[gg * 192 + k];
    else {
        int kk = k - 64; float s = 0.f;
        for (int j = 0; j < 128; j++) s += W_ih[gg * 192 + 64 + j] * W3[j * 96 + kk];
        v = s;
    }
    Wni[idx] = v;
}

__global__ __launch_bounds__(256) void k_vb3(const float* __restrict__ W_ih,
                                             const float* __restrict__ b3,
                                             float* __restrict__ vb3) {
    int g = blockIdx.x * 256 + threadIdx.x;
    if (g >= 384) return;
    float s = 0.f;
    for (int j = 0; j < 128; j++) s += W_ih[g * 192 + 64 + j] * b3[j];
    vb3[g] = s;
}

__global__ __launch_bounds__(256) void k_bsum(const float* __restrict__ b_ih,
                                              const float* __restrict__ b_hh,
                                              float* __restrict__ bsum) {
    int d = blockIdx.x * 256 + threadIdx.x;
    if (d >= 384) return;
    bsum[d] = b_ih[d] + (d < 256 ? b_hh[d] : 0.f);
}

// ---------------------------------------------------------------------------
// Pack: src fp32 (ld), element (row0+j, k) -> A-frags [Mt][KT][64][8]
__global__ __launch_bounds__(256) void k_pack2(const float* __restrict__ src,
                                               unsigned short* __restrict__ out,
                                               int Mt, int KT, int ld, int row0) {
    int idx = blockIdx.x * 256 + threadIdx.x;
    if (idx >= Mt * KT * 512) return;
    int jj = idx & 7;
    int l  = (idx >> 3) & 63;
    int tile = idx >> 9;
    int kt = tile % KT;
    int mt = tile / KT;
    int j = row0 + mt * 16 + (l & 15);
    int k = kt * 32 + (l >> 4) * 8 + jj;
    out[idx] = f2bf(src[(size_t)j * ld + k]);
}

// ---------------------------------------------------------------------------
// CSR build (once; ids fixed across iterations)
__global__ __launch_bounds__(256) void k_hist(const int* __restrict__ dst,
                                              int* __restrict__ counts) {
    int e = blockIdx.x * 256 + threadIdx.x;
    if (e < N_EDGES) atomicAdd(&counts[dst[e]], 1);
}

__global__ __launch_bounds__(1024) void k_scan(const int* __restrict__ counts,
                                               int* __restrict__ row_off) {
    __shared__ int sh[1024];
    int t = threadIdx.x;
    const int STR = 49;
    int base = t * STR;
    int s = 0;
    for (int i = 0; i < STR; i++) {
        int n = base + i;
        if (n < N_NODES) s += counts[n];
    }
    sh[t] = s;
    __syncthreads();
    for (int off = 1; off < 1024; off <<= 1) {
        int v = (t >= off) ? sh[t - off] : 0;
        __syncthreads();
        sh[t] += v;
        __syncthreads();
    }
    int run = (t == 0) ? 0 : sh[t - 1];
    for (int i = 0; i < STR; i++) {
        int n = base + i;
        if (n < N_NODES) { row_off[n] = run; run += counts[n]; }
    }
    if (t == 1023) row_off[N_NODES] = run;
}

__global__ __launch_bounds__(256) void k_permute(const int* __restrict__ src,
                                                 const int* __restrict__ dst,
                                                 const int* __restrict__ row_off,
                                                 int* __restrict__ cursor,
                                                 int* __restrict__ perm_src,
                                                 int* __restrict__ perm_dst) {
    int e = blockIdx.x * 256 + threadIdx.x;
    if (e >= N_EDGES) return;
    int d = dst[e];
    int pos = row_off[d] + atomicAdd(&cursor[d], 1);
    perm_src[pos] = src[e];
    perm_dst[pos] = d;
}

// ---------------------------------------------------------------------------
// Fused edge MLP + aggregation, LOW-VGPR variant (target <=128 => 2 blocks/CU;
// R5@88/R14@128 co-resided 2 blocks, R6@220/R11@236/R15@188 stuck at 1).
// W1+W2 both LDS-cached (R15: global MFMA operands = 2x slowdown).
// Single fr[4] buffer in 3-phase rotation: MFMA(src) -> load dst ->
// MFMA(dst) -> prefetch next src (hidden under relay/L2/scan).
// Register carry chain; plain float4 stores for interior nodes; atomics only
// at wave-range boundaries; DPP segmented scan; setprio around MFMA.
__global__ __launch_bounds__(256) void k_edge_fused(
    const unsigned short* __restrict__ hbf,   // [N][128] bf16
    const int* __restrict__ perm_src, const int* __restrict__ perm_dst,
    const short8* __restrict__ W1Ag,          // [6*8*64] frags
    const short8* __restrict__ W2Ag,          // [6*3*64] frags
    const float* __restrict__ b1,
    const float* __restrict__ b2,
    float* __restrict__ r2agg)                // [NPAD][96]
{
    __shared__ __attribute__((aligned(16))) short8 W1s[6 * 8 * 64];      // 49152 B
    __shared__ __attribute__((aligned(16))) short8 W2s[6 * 3 * 64];      // 18432 B
    __shared__ __attribute__((aligned(16))) unsigned short relay[4][16][AROW]; // 13312 B

    int t = threadIdx.x;
    int w = t >> 6, l = t & 63;
    int col = l & 15, krow = l >> 4;

    for (int i = t; i < 6 * 8 * 64; i += 256) W1s[i] = W1Ag[i];
    for (int i = t; i < 6 * 3 * 64; i += 256) W2s[i] = W2Ag[i];
    __syncthreads();   // only barrier in the kernel

    int wtid = blockIdx.x * 4 + w;
    int tlo = wtid * TPW;
    int thi = tlo + TPW; if (thi > NT16) thi = NT16;
    if (tlo >= thi) return;

    float carry[24];
#pragma unroll
    for (int q = 0; q < 24; q++) carry[q] = 0.f;
    bool head = true;   // carry chain touches the wave's first edge

    int sid, did, sidN = 0, didN = 0;
    { int e = tlo * 16 + col; sid = perm_src[e]; did = perm_dst[e]; }

    short8 fr[4];
    {   // prefetch src half of first tile
        const unsigned short* sr = hbf + (size_t)sid * 128 + krow * 8;
#pragma unroll
        for (int kt = 0; kt < 4; kt++) fr[kt] = *(const short8*)(sr + kt * 32);
    }

    for (int tt = tlo; tt < thi; ++tt) {
        bool hasN = (tt + 1 < thi);
        if (hasN) { int e = (tt + 1) * 16 + col; sidN = perm_src[e]; didN = perm_dst[e]; }

        int dp = __shfl_up(did, 1);
        unsigned m16 = (unsigned)__ballot((col == 0) || (did != dp)) & 0xFFFFu;
        bool continuing = hasN && (__shfl(did, 15) == __shfl(didN, 0));

        // ---- L1 src half ----
        f32x4 c1[6] = {};
        __builtin_amdgcn_s_setprio(1);
#pragma unroll
        for (int kt = 0; kt < 4; kt++) {
#pragma unroll
            for (int mt = 0; mt < 6; mt++)
                c1[mt] = __builtin_amdgcn_mfma_f32_16x16x32_bf16(W1s[(mt * 8 + kt) * 64 + l], fr[kt], c1[mt], 0, 0, 0);
        }
        __builtin_amdgcn_s_setprio(0);
        // ---- load dst half (fr reuse) ----
        {
            const unsigned short* dr = hbf + (size_t)did * 128 + krow * 8;
#pragma unroll
            for (int kt = 0; kt < 4; kt++) fr[kt] = *(const short8*)(dr + kt * 32);
        }
        __builtin_amdgcn_s_setprio(1);
#pragma unroll
        for (int kt = 0; kt < 4; kt++) {
#pragma unroll
            for (int mt = 0; mt < 6; mt++)
                c1[mt] = __builtin_amdgcn_mfma_f32_16x16x32_bf16(W1s[(mt * 8 + 4 + kt) * 64 + l], fr[kt], c1[mt], 0, 0, 0);
        }
        __builtin_amdgcn_s_setprio(0);

        // ---- prefetch next tile's src half (latency hidden under L2+scan) ----
        if (hasN) {
            const unsigned short* sr = hbf + (size_t)sidN * 128 + krow * 8;
#pragma unroll
            for (int kt = 0; kt < 4; kt++) fr[kt] = *(const short8*)(sr + kt * 32);
        }

        // ---- a1 epilogue -> wave-private LDS relay ----
#pragma unroll
        for (int mt = 0; mt < 6; mt++) {
#pragma unroll
            for (int r = 0; r < 4; r += 2) {
                int j0 = mt * 16 + krow * 4 + r;
                float v0 = fmaxf(c1[mt][r]     + b1[j0],     0.f);
                float v1 = fmaxf(c1[mt][r + 1] + b1[j0 + 1], 0.f);
                *(unsigned int*)(&relay[w][col][j0]) = cvt_pk_bf16(v0, v1);
            }
        }
        // ---- L2 ----
        f32x4 c2[6] = {};
        __builtin_amdgcn_s_setprio(1);
#pragma unroll
        for (int kt = 0; kt < 3; kt++) {
            short8 b = *(const short8*)(&relay[w][col][kt * 32 + krow * 8]);
#pragma unroll
            for (int mt = 0; mt < 6; mt++)
                c2[mt] = __builtin_amdgcn_mfma_f32_16x16x32_bf16(W2s[(mt * 3 + kt) * 64 + l], b, c2[mt], 0, 0, 0);
        }
        __builtin_amdgcn_s_setprio(0);
        // ---- msg (bias+relu); inject carry at col0 ----
        float s[24];
#pragma unroll
        for (int mt = 0; mt < 6; mt++)
#pragma unroll
            for (int r = 0; r < 4; r++) {
                int j = mt * 16 + krow * 4 + r;
                float v = fmaxf(c2[mt][r] + b2[j], 0.f);
                s[mt * 4 + r] = v + ((col == 0) ? carry[mt * 4 + r] : 0.f);
            }
        // ---- segmented inclusive scan over col ----
        unsigned fl = (m16 >> col) & 1u;
        seg_step<0x111>(s, fl);
        seg_step<0x112>(s, fl);
        seg_step<0x114>(s, fl);
        seg_step<0x118>(s, fl);
        // ---- emission ----
        bool is_end = (col == 15) || ((m16 >> (col + 1)) & 1u);
        if (is_end && !((col == 15) && continuing)) {
            unsigned lowmask = (2u << col) - 1u;
            bool first_seg = (__popc(m16 & lowmask) == 1);
            bool use_atomic = (first_seg && head) || ((col == 15) && !hasN);
            float* base = r2agg + (size_t)did * 96 + krow * 4;
            if (use_atomic) {
#pragma unroll
                for (int mt = 0; mt < 6; mt++)
#pragma unroll
                    for (int r = 0; r < 4; r++)
                        atomicAdd(base + mt * 16 + r, s[mt * 4 + r]);
            } else {
#pragma unroll
                for (int mt = 0; mt < 6; mt++)
                    *(float4*)(base + mt * 16) = make_float4(s[mt * 4], s[mt * 4 + 1],
                                                             s[mt * 4 + 2], s[mt * 4 + 3]);
            }
        }
        // ---- carry update (wave-uniform) ----
        if (continuing) {
            head = head && (m16 == 1u);
#pragma unroll
            for (int q = 0; q < 24; q++) carry[q] = ror_prev(s[q]);
        } else {
            head = false;
#pragma unroll
            for (int q = 0; q < 24; q++) carry[q] = 0.f;
        }
        sid = sidN; did = didN;
    }
}

// ---------------------------------------------------------------------------
// Node phase: 4 waves x 64 shared nodes; wave w owns d-range [32w,32w+32)
// of all gates (and out rows [16w,16w+16)). Weights read once per wave with
// x4 B-frag reuse. 3 barriers, no weight staging.
__global__ __launch_bounds__(256) void k_node_mfma(
    const float* __restrict__ inp,      // [N][64]
    const float* __restrict__ r2agg,    // [NPAD][96]
    const int* __restrict__ row_off,    // [N+1]
    float* __restrict__ h,              // [N][128] fp32 in/out
    unsigned short* __restrict__ hbf,   // [N][128] bf16 in/out
    const short8* __restrict__ WbigA,   // [16][9] tiles
    const short8* __restrict__ WniA,    // [8][5]
    const short8* __restrict__ WnhA,    // [8][4]
    const short8* __restrict__ WoutA,   // [4][4]
    const float* __restrict__ vb3,
    const float* __restrict__ bsum,
    const float* __restrict__ b_hh,
    const float* __restrict__ b_out,
    float* __restrict__ out, int iter)
{
    __shared__ __attribute__((aligned(16))) unsigned short X[4][16][XROW]; // 37888 B
    __shared__ float degs[64];
    int t = threadIdx.x;
    int w = t >> 6, l = t & 63;
    int nb = blockIdx.x * 64;
    int col = l & 15, krow = l >> 4;

    // ---- stage X = [inp(64) | r2(96) | h(128)] bf16 + degs ----
    for (int idx = t; idx < 64 * 32; idx += 256) {
        int i = idx >> 5, kk = (idx & 31) << 1;
        int n = nb + i;
        float2 v = make_float2(0.f, 0.f);
        if (n < N_NODES) v = *(const float2*)(inp + (size_t)n * 64 + kk);
        *(unsigned int*)(&X[i >> 4][i & 15][kk]) = cvt_pk_bf16(v.x, v.y);
    }
    for (int idx = t; idx < 64 * 48; idx += 256) {      // r2 node-major pairs
        int i = (int)((unsigned)idx / 48u), kp = idx - i * 48;
        int n = nb + i;
        float2 v = make_float2(0.f, 0.f);
        if (n < N_NODES) v = *(const float2*)(r2agg + (size_t)n * 96 + kp * 2);
        *(unsigned int*)(&X[i >> 4][i & 15][64 + kp * 2]) = cvt_pk_bf16(v.x, v.y);
    }
    for (int idx = t; idx < 64 * 16; idx += 256) {
        int i = idx >> 4, c = idx & 15;
        int n = nb + i;
        uint4 v = make_uint4(0, 0, 0, 0);
        if (n < N_NODES) v = ((const uint4*)(hbf + (size_t)n * 128))[c];
        *(uint4*)(&X[i >> 4][i & 15][160 + c * 8]) = v;
    }
    if (t < 64) {
        int n = nb + t;
        degs[t] = (n < N_NODES) ? (float)(row_off[n + 1] - row_off[n]) : 0.f;
    }
    __syncthreads();

    // ---- GEMMs: wave w computes d in [32w, 32w+32) ----
    int mts[4] = {2 * w, 2 * w + 1, 8 + 2 * w, 9 + 2 * w};   // r lo/hi, z lo/hi
    f32x4 cg[4][4] = {};
#pragma unroll 3
    for (int kt = 0; kt < 9; kt++) {
        short8 b[4];
#pragma unroll
        for (int bf = 0; bf < 4; bf++) b[bf] = *(const short8*)(&X[bf][col][kt * 32 + krow * 8]);
#pragma unroll
        for (int mi = 0; mi < 4; mi++) {
            short8 a = WbigA[(mts[mi] * 9 + kt) * 64 + l];
#pragma unroll
            for (int bf = 0; bf < 4; bf++)
                cg[mi][bf] = __builtin_amdgcn_mfma_f32_16x16x32_bf16(a, b[bf], cg[mi][bf], 0, 0, 0);
        }
    }
    f32x4 ci[2][4] = {};
#pragma unroll
    for (int kt = 0; kt < 5; kt++) {
        short8 b[4];
#pragma unroll
        for (int bf = 0; bf < 4; bf++) b[bf] = *(const short8*)(&X[bf][col][kt * 32 + krow * 8]);
#pragma unroll
        for (int mi = 0; mi < 2; mi++) {
            short8 a = WniA[((2 * w + mi) * 5 + kt) * 64 + l];
#pragma unroll
            for (int bf = 0; bf < 4; bf++)
                ci[mi][bf] = __builtin_amdgcn_mfma_f32_16x16x32_bf16(a, b[bf], ci[mi][bf], 0, 0, 0);
        }
    }
    f32x4 ch[2][4] = {};
#pragma unroll
    for (int kt = 0; kt < 4; kt++) {
        short8 b[4];
#pragma unroll
        for (int bf = 0; bf < 4; bf++) b[bf] = *(const short8*)(&X[bf][col][160 + kt * 32 + krow * 8]);
#pragma unroll
        for (int mi = 0; mi < 2; mi++) {
            short8 a = WnhA[((2 * w + mi) * 4 + kt) * 64 + l];
#pragma unroll
            for (int bf = 0; bf < 4; bf++)
                ch[mi][bf] = __builtin_amdgcn_mfma_f32_16x16x32_bf16(a, b[bf], ch[mi][bf], 0, 0, 0);
        }
    }
    __syncthreads();   // all reads of old-h in X complete

    // ---- GRU epilogue: wave w writes d-range [32w,32w+32) for all 64 nodes ----
#pragma unroll
    for (int mi = 0; mi < 2; mi++) {
        int d0 = w * 32 + mi * 16 + krow * 4;
        float4 bsr = *(const float4*)(bsum + d0);
        float4 bsz = *(const float4*)(bsum + 128 + d0);
        float4 bsn = *(const float4*)(bsum + 256 + d0);
        float4 vbr = *(const float4*)(vb3 + d0);
        float4 vbz = *(const float4*)(vb3 + 128 + d0);
        float4 vbn = *(const float4*)(vb3 + 256 + d0);
        float4 bhn = *(const float4*)(b_hh + 256 + d0);
        float bsrv[4] = {bsr.x, bsr.y, bsr.z, bsr.w};
        float bszv[4] = {bsz.x, bsz.y, bsz.z, bsz.w};
        float bsnv[4] = {bsn.x, bsn.y, bsn.z, bsn.w};
        float vbrv[4] = {vbr.x, vbr.y, vbr.z, vbr.w};
        float vbzv[4] = {vbz.x, vbz.y, vbz.z, vbz.w};
        float vbnv[4] = {vbn.x, vbn.y, vbn.z, vbn.w};
        float bhnv[4] = {bhn.x, bhn.y, bhn.z, bhn.w};
#pragma unroll
        for (int bf = 0; bf < 4; bf++) {
            int n = nb + bf * 16 + col;
            bool valid = (n < N_NODES);
            float deg = degs[bf * 16 + col];
            float4 ho = make_float4(0.f, 0.f, 0.f, 0.f);
            if (valid) ho = *(const float4*)(h + (size_t)n * 128 + d0);
            float hov[4] = {ho.x, ho.y, ho.z, ho.w};
            float hv[4];
#pragma unroll
            for (int r = 0; r < 4; r++) {
                float rp = cg[mi][bf][r]     + bsrv[r] + deg * vbrv[r];
                float zp = cg[2 + mi][bf][r] + bszv[r] + deg * vbzv[r];
                float ip = ci[mi][bf][r]     + bsnv[r] + deg * vbnv[r];
                float hp = ch[mi][bf][r]     + bhnv[r];
                float rg = 1.f / (1.f + __expf(-rp));
                float zg = 1.f / (1.f + __expf(-zp));
                float ng = fast_tanh(ip + rg * hp);
                hv[r] = (1.f - zg) * ng + zg * hov[r];
            }
            if (valid)
                *(float4*)(h + (size_t)n * 128 + d0) = make_float4(hv[0], hv[1], hv[2], hv[3]);
            *(unsigned int*)(&X[bf][col][160 + d0])     = cvt_pk_bf16(hv[0], hv[1]);
            *(unsigned int*)(&X[bf][col][160 + d0 + 2]) = cvt_pk_bf16(hv[2], hv[3]);
        }
    }
    __syncthreads();   // h_new complete in X

    // ---- out projection: wave w computes rows [16w,16w+16) ----
    f32x4 co[4] = {};
#pragma unroll
    for (int kt = 0; kt < 4; kt++) {
        short8 a = WoutA[(w * 4 + kt) * 64 + l];
#pragma unroll
        for (int bf = 0; bf < 4; bf++) {
            short8 b = *(const short8*)(&X[bf][col][160 + kt * 32 + krow * 8]);
            co[bf] = __builtin_amdgcn_mfma_f32_16x16x32_bf16(a, b, co[bf], 0, 0, 0);
        }
    }
    {
        int o0 = w * 16 + krow * 4;
        float4 bo = *(const float4*)(b_out + o0);
#pragma unroll
        for (int bf = 0; bf < 4; bf++) {
            int n = nb + bf * 16 + col;
            if (n < N_NODES) {
                float* op = out + (size_t)iter * N_NODES * 64 + (size_t)n * 64 + o0;
                *(float4*)op = make_float4(co[bf][0] + bo.x, co[bf][1] + bo.y,
                                           co[bf][2] + bo.z, co[bf][3] + bo.w);
            }
        }
    }

    // ---- hbf writeback ----
    for (int idx = t; idx < 64 * 16; idx += 256) {
        int i = idx >> 4, c = idx & 15;
        int n2 = nb + i;
        if (n2 < N_NODES)
            ((uint4*)(hbf + (size_t)n2 * 128))[c] = *(const uint4*)(&X[i >> 4][i & 15][160 + c * 8]);
    }
}

// ---------------------------------------------------------------------------
extern "C" void kernel_launch(void* const* d_in, const int* in_sizes, int n_in,
                              void* d_out, int out_size, void* d_ws, size_t ws_size,
                              hipStream_t stream)
{
    const float* inp   = (const float*)d_in[0];
    const int*   src   = (const int*)d_in[1];
    const int*   dst   = (const int*)d_in[2];
    const float* W1    = (const float*)d_in[3];
    const float* b1    = (const float*)d_in[4];
    const float* W2    = (const float*)d_in[5];
    const float* b2    = (const float*)d_in[6];
    const float* W3    = (const float*)d_in[7];
    const float* b3    = (const float*)d_in[8];
    const float* W_ih  = (const float*)d_in[9];
    const float* W_hh  = (const float*)d_in[10];
    const float* b_ih  = (const float*)d_in[11];
    const float* b_hh  = (const float*)d_in[12];
    const float* W_out = (const float*)d_in[13];
    const float* b_out = (const float*)d_in[14];
    float* out = (float*)d_out;

    char* ws = (char*)d_ws;
    size_t off = 0;
    auto alloc = [&](size_t bytes) -> void* {
        void* p = ws + off;
        off += (bytes + 255) & ~(size_t)255;
        return p;
    };
    float* h       = (float*)alloc((size_t)N_NODES * 128 * 4);
    unsigned short* hbf = (unsigned short*)alloc((size_t)N_NODES * 128 * 2);
    float* r2agg   = (float*)alloc((size_t)NPAD * 96 * 4);
    float* Wbig    = (float*)alloc((size_t)256 * 288 * 4);
    float* Wni     = (float*)alloc((size_t)128 * 160 * 4);
    float* vb3     = (float*)alloc((size_t)384 * 4);
    float* bsum    = (float*)alloc((size_t)384 * 4);
    unsigned short* W1A   = (unsigned short*)alloc((size_t)6 * 8 * 512 * 2);
    unsigned short* W2A   = (unsigned short*)alloc((size_t)6 * 3 * 512 * 2);
    unsigned short* WbigA = (unsigned short*)alloc((size_t)16 * 9 * 512 * 2);
    unsigned short* WniA  = (unsigned short*)alloc((size_t)8 * 5 * 512 * 2);
    unsigned short* WnhA  = (unsigned short*)alloc((size_t)8 * 4 * 512 * 2);
    unsigned short* WoutA = (unsigned short*)alloc((size_t)4 * 4 * 512 * 2);
    int*   counts  = (int*)alloc((size_t)N_NODES * 4);
    int*   cursor  = (int*)alloc((size_t)N_NODES * 4);
    int*   row_off = (int*)alloc((size_t)(N_NODES + 1) * 4);
    int*   perm_src= (int*)alloc((size_t)N_EDGES * 4);
    int*   perm_dst= (int*)alloc((size_t)N_EDGES * 4);

    // ---- one-time preprocessing ----
    hipMemsetAsync(h, 0, (size_t)N_NODES * 128 * 4, stream);
    hipMemsetAsync(hbf, 0, (size_t)N_NODES * 128 * 2, stream);
    hipMemsetAsync(counts, 0, (size_t)N_NODES * 4, stream);
    hipMemsetAsync(cursor, 0, (size_t)N_NODES * 4, stream);

    k_build_wbig<<<(256 * 288 + 255) / 256, 256, 0, stream>>>(W_ih, W3, W_hh, Wbig);
    k_build_wni<<<(128 * 160 + 255) / 256, 256, 0, stream>>>(W_ih, W3, Wni);
    k_vb3<<<2, 256, 0, stream>>>(W_ih, b3, vb3);
    k_bsum<<<2, 256, 0, stream>>>(b_ih, b_hh, bsum);

    k_pack2<<<(6 * 8 * 512 + 255) / 256, 256, 0, stream>>>(W1, W1A, 6, 8, 256, 0);
    k_pack2<<<(6 * 3 * 512 + 255) / 256, 256, 0, stream>>>(W2, W2A, 6, 3, 96, 0);
    k_pack2<<<(16 * 9 * 512 + 255) / 256, 256, 0, stream>>>(Wbig, WbigA, 16, 9, 288, 0);
    k_pack2<<<(8 * 5 * 512 + 255) / 256, 256, 0, stream>>>(Wni, WniA, 8, 5, 160, 0);
    k_pack2<<<(8 * 4 * 512 + 255) / 256, 256, 0, stream>>>(W_hh, WnhA, 8, 4, 128, 256);
    k_pack2<<<(4 * 4 * 512 + 255) / 256, 256, 0, stream>>>(W_out, WoutA, 4, 4, 128, 0);

    k_hist<<<(N_EDGES + 255) / 256, 256, 0, stream>>>(dst, counts);
    k_scan<<<1, 1024, 0, stream>>>(counts, row_off);
    k_permute<<<(N_EDGES + 255) / 256, 256, 0, stream>>>(src, dst, row_off, cursor,
                                                         perm_src, perm_dst);

    // ---- iterations ----
    for (int it = 0; it < N_ITERS; ++it) {
        hipMemsetAsync(r2agg, 0, (size_t)NPAD * 96 * 4, stream);
        k_edge_fused<<<512, 256, 0, stream>>>(hbf, perm_src, perm_dst,
                                              (const short8*)W1A, (const short8*)W2A,
                                              b1, b2, r2agg);
        k_node_mfma<<<(N_NODES + 63) / 64, 256, 0, stream>>>(inp, r2agg, row_off, h, hbf,
                                                     (const short8*)WbigA, (const short8*)WniA,
                                                     (const short8*)WnhA, (const short8*)WoutA,
                                                     vb3, bsum, b_hh, b_out, out, it);
    }
}

// Round 17
// 1703.112 us; speedup vs baseline: 2.0770x; 1.1576x over previous
//
#include <hip/hip_runtime.h>

#define N_NODES 50000
#define N_EDGES 800000
#define N_ITERS 7
#define NPAD 50048
#define NT16 (N_EDGES / 16)   // 50000 16-edge tiles
#define TOTP 1024             // 512 blocks x 2 pairs
#define TPP ((NT16 + TOTP - 1) / TOTP)   // 49 tiles per pair

typedef __attribute__((ext_vector_type(8))) short short8;
typedef __attribute__((ext_vector_type(4))) float f32x4;

#define AROW 104   // pair-shared relay row: 96 bf16 + 8 pad
#define XROW 296   // X row: 288 bf16 + 8 pad

static __device__ __forceinline__ unsigned short f2bf(float f) {
    unsigned int u = __float_as_uint(f);
    unsigned int r = (u + 0x7fffu + ((u >> 16) & 1u)) >> 16;
    return (unsigned short)r;
}
static __device__ __forceinline__ float bf2f(unsigned short u) {
    return __uint_as_float(((unsigned int)u) << 16);
}
// pack two f32 -> 2x bf16 (RNE), lo in bits [15:0]
static __device__ __forceinline__ unsigned cvt_pk_bf16(float lo, float hi) {
    unsigned r;
    asm("v_cvt_pk_bf16_f32 %0, %1, %2" : "=v"(r) : "v"(lo), "v"(hi));
    return r;
}
static __device__ __forceinline__ float fast_tanh(float x) {
    float xc = fminf(fmaxf(x, -15.f), 15.f);
    float t = __expf(2.f * xc);
    return (t - 1.f) / (t + 1.f);
}
// row_ror:1 (0x121): lane i <- lane (i-1) mod 16, so col0 receives col15.
static __device__ __forceinline__ float ror_prev(float x) {
    return __int_as_float(__builtin_amdgcn_update_dpp(0, __float_as_int(x), 0x121, 0xf, 0xf, true));
}

// one segmented-scan step over the 16-lane row group (row_shr:CTRL&15, bound_ctrl=1)
template <int CTRL, int N>
static __device__ __forceinline__ void seg_step(float (&s)[N], unsigned& fl) {
    unsigned fv = (unsigned)__builtin_amdgcn_update_dpp(0, (int)fl, CTRL, 0xf, 0xf, true);
    float g = fl ? 0.f : 1.f;
#pragma unroll
    for (int q = 0; q < N; q++) {
        int sv = __builtin_amdgcn_update_dpp(0, __float_as_int(s[q]), CTRL, 0xf, 0xf, true);
        s[q] += __int_as_float(sv) * g;
    }
    fl |= fv;
}

// ---------------------------------------------------------------------------
// Wbig [256][288]: rows = r,z gates; cols = [W_ih[:, :64] | W_ih[:,64:]@W3 | W_hh]
__global__ __launch_bounds__(256) void k_build_wbig(const float* __restrict__ W_ih,
                                                    const float* __restrict__ W3,
                                                    const float* __restrict__ W_hh,
                                                    float* __restrict__ Wbig) {
    int idx = blockIdx.x * 256 + threadIdx.x;
    if (idx >= 256 * 288) return;
    int g = idx / 288, k = idx - g * 288;
    float v;
    if (k < 64) v = W_ih[g * 192 + k];
    else if (k < 160) {
        int kk = k - 64; float s = 0.f;
        for (int j = 0; j < 128; j++) s += W_ih[g * 192 + 64 + j] * W3[j * 96 + kk];
        v = s;
    } else v = W_hh[g * 128 + (k - 160)];
    Wbig[idx] = v;
}

// Wni [128][160]: n-gate input part (W_ih rows 256..383, with W3 fold)
__global__ __launch_bounds__(256) void k_build_wni(const float* __restrict__ W_ih,
                                                   const float* __restrict__ W3,
                                                   float* __restrict__ Wni) {
    int idx = blockIdx.x * 256 + threadIdx.x;
    if (idx >= 128 * 160) return;
    int g = idx / 160, k = idx - g * 160;
    int gg = 256 + g;
    float v;
    if (k < 64) v = W_ih[gg * 192 + k];
    else {
        int kk = k - 64; float s = 0.f;
        for (int j = 0; j < 128; j++) s += W_ih[gg * 192 + 64 + j] * W3[j * 96 + kk];
        v = s;
    }
    Wni[idx] = v;
}

__global__ __launch_bounds__(256) void k_vb3(const float* __restrict__ W_ih,
                                             const float* __restrict__ b3,
                                             float* __restrict__ vb3) {
    int g = blockIdx.x * 256 + threadIdx.x;
    if (g >= 384) return;
    float s = 0.f;
    for (int j = 0; j < 128; j++) s += W_ih[g * 192 + 64 + j] * b3[j];
    vb3[g] = s;
}

__global__ __launch_bounds__(256) void k_bsum(const float* __restrict__ b_ih,
                                              const float* __restrict__ b_hh,
                                              float* __restrict__ bsum) {
    int d = blockIdx.x * 256 + threadIdx.x;
    if (d >= 384) return;
    bsum[d] = b_ih[d] + (d < 256 ? b_hh[d] : 0.f);
}

// ---------------------------------------------------------------------------
// Pack: src fp32 (ld), element (row0+j, k) -> A-frags [Mt][KT][64][8]
__global__ __launch_bounds__(256) void k_pack2(const float* __restrict__ src,
                                               unsigned short* __restrict__ out,
                                               int Mt, int KT, int ld, int row0) {
    int idx = blockIdx.x * 256 + threadIdx.x;
    if (idx >= Mt * KT * 512) return;
    int jj = idx & 7;
    int l  = (idx >> 3) & 63;
    int tile = idx >> 9;
    int kt = tile % KT;
    int mt = tile / KT;
    int j = row0 + mt * 16 + (l & 15);
    int k = kt * 32 + (l >> 4) * 8 + jj;
    out[idx] = f2bf(src[(size_t)j * ld + k]);
}

// ---------------------------------------------------------------------------
// CSR build (once; ids fixed across iterations)
__global__ __launch_bounds__(256) void k_hist(const int* __restrict__ dst,
                                              int* __restrict__ counts) {
    int e = blockIdx.x * 256 + threadIdx.x;
    if (e < N_EDGES) atomicAdd(&counts[dst[e]], 1);
}

__global__ __launch_bounds__(1024) void k_scan(const int* __restrict__ counts,
                                               int* __restrict__ row_off) {
    __shared__ int sh[1024];
    int t = threadIdx.x;
    const int STR = 49;
    int base = t * STR;
    int s = 0;
    for (int i = 0; i < STR; i++) {
        int n = base + i;
        if (n < N_NODES) s += counts[n];
    }
    sh[t] = s;
    __syncthreads();
    for (int off = 1; off < 1024; off <<= 1) {
        int v = (t >= off) ? sh[t - off] : 0;
        __syncthreads();
        sh[t] += v;
        __syncthreads();
    }
    int run = (t == 0) ? 0 : sh[t - 1];
    for (int i = 0; i < STR; i++) {
        int n = base + i;
        if (n < N_NODES) { row_off[n] = run; run += counts[n]; }
    }
    if (t == 1023) row_off[N_NODES] = run;
}

__global__ __launch_bounds__(256) void k_permute(const int* __restrict__ src,
                                                 const int* __restrict__ dst,
                                                 const int* __restrict__ row_off,
                                                 int* __restrict__ cursor,
                                                 int* __restrict__ perm_src,
                                                 int* __restrict__ perm_dst) {
    int e = blockIdx.x * 256 + threadIdx.x;
    if (e >= N_EDGES) return;
    int d = dst[e];
    int pos = row_off[d] + atomicAdd(&cursor[d], 1);
    perm_src[pos] = src[e];
    perm_dst[pos] = d;
}

// ---------------------------------------------------------------------------
// Fused edge MLP + aggregation, SPLIT-M wave pairs for <=128 VGPR.
// Waves (2p,2p+1) co-process the same 16-edge tile; wave u owns neurons
// [48u,48u+48): c1[3]+c2[3]+s[12]+carry[12]+fr[4] ~ 105 VGPR (R16's 24-wide
// lane state was 160 -> 1 wave/SIMD). Occupancy law (7 pts): VGPR<=128 ->
// 2 blocks/CU, >128 -> 1. Fixed TPP loop with `active` predication so the
// 2 barriers/tile can't deadlock on ragged tails. Gathers duplicated per
// pair (L2-resident). Carry chain / DPP scan / emission as before.
__global__ __launch_bounds__(256) void k_edge_fused(
    const unsigned short* __restrict__ hbf,   // [N][128] bf16
    const int* __restrict__ perm_src, const int* __restrict__ perm_dst,
    const short8* __restrict__ W1Ag,          // [6*8*64] frags
    const short8* __restrict__ W2Ag,          // [6*3*64] frags
    const float* __restrict__ b1,
    const float* __restrict__ b2,
    float* __restrict__ r2agg)                // [NPAD][96]
{
    __shared__ __attribute__((aligned(16))) short8 W1s[6 * 8 * 64];      // 49152 B
    __shared__ __attribute__((aligned(16))) short8 W2s[6 * 3 * 64];      // 18432 B
    __shared__ __attribute__((aligned(16))) unsigned short relay[2][16][AROW]; // 6656 B

    int t = threadIdx.x;
    int w = t >> 6, l = t & 63;
    int col = l & 15, krow = l >> 4;
    int pair = w >> 1;          // 0..1
    int u = w & 1;              // M-half: neurons [48u, 48u+48)
    int mtb = 3 * u;            // global mt base

    for (int i = t; i < 6 * 8 * 64; i += 256) W1s[i] = W1Ag[i];
    for (int i = t; i < 6 * 3 * 64; i += 256) W2s[i] = W2Ag[i];
    __syncthreads();

    int pidx = blockIdx.x * 2 + pair;
    int tlo = pidx * TPP;
    int thi = tlo + TPP; if (thi > NT16) thi = NT16;
    int ntiles = thi - tlo; if (ntiles < 0) ntiles = 0;

    float carry[12];
#pragma unroll
    for (int q = 0; q < 12; q++) carry[q] = 0.f;
    bool head = true;

    // preload first tile ids + src frags (clamped for inactive pairs)
    int te0 = tlo; if (te0 >= NT16) te0 = NT16 - 1;
    int sid, did;
    { int e = te0 * 16 + col; sid = perm_src[e]; did = perm_dst[e]; }
    short8 fr[4];
    {
        const unsigned short* sr = hbf + (size_t)sid * 128 + krow * 8;
#pragma unroll
        for (int kt = 0; kt < 4; kt++) fr[kt] = *(const short8*)(sr + kt * 32);
    }

    for (int tt = 0; tt < TPP; ++tt) {
        bool active = (tt < ntiles);
        bool hasN = (tt + 1 < ntiles);
        // next tile ids (clamped; harmless when inactive)
        int teN = tlo + tt + 1; if (teN >= NT16) teN = NT16 - 1;
        int sidN, didN;
        { int e = teN * 16 + col; sidN = perm_src[e]; didN = perm_dst[e]; }

        int dp = __shfl_up(did, 1);
        unsigned m16 = (unsigned)__ballot((col == 0) || (did != dp)) & 0xFFFFu;
        bool continuing = hasN && (__shfl(did, 15) == __shfl(didN, 0));

        // ---- L1 src half: 3 mt x 4 kt ----
        f32x4 c1[3] = {};
        __builtin_amdgcn_s_setprio(1);
#pragma unroll
        for (int kt = 0; kt < 4; kt++) {
#pragma unroll
            for (int mt = 0; mt < 3; mt++)
                c1[mt] = __builtin_amdgcn_mfma_f32_16x16x32_bf16(W1s[((mtb + mt) * 8 + kt) * 64 + l], fr[kt], c1[mt], 0, 0, 0);
        }
        __builtin_amdgcn_s_setprio(0);
        // ---- load dst half (reuse fr) ----
        {
            const unsigned short* dr = hbf + (size_t)did * 128 + krow * 8;
#pragma unroll
            for (int kt = 0; kt < 4; kt++) fr[kt] = *(const short8*)(dr + kt * 32);
        }
        __builtin_amdgcn_s_setprio(1);
#pragma unroll
        for (int kt = 0; kt < 4; kt++) {
#pragma unroll
            for (int mt = 0; mt < 3; mt++)
                c1[mt] = __builtin_amdgcn_mfma_f32_16x16x32_bf16(W1s[((mtb + mt) * 8 + 4 + kt) * 64 + l], fr[kt], c1[mt], 0, 0, 0);
        }
        __builtin_amdgcn_s_setprio(0);
        // ---- prefetch next tile's src half (hidden under relay/L2/scan) ----
        {
            const unsigned short* sr = hbf + (size_t)sidN * 128 + krow * 8;
#pragma unroll
            for (int kt = 0; kt < 4; kt++) fr[kt] = *(const short8*)(sr + kt * 32);
        }

        // ---- a1 epilogue: wave writes its 48 dims of the pair relay ----
#pragma unroll
        for (int mt = 0; mt < 3; mt++) {
#pragma unroll
            for (int r = 0; r < 4; r += 2) {
                int j0 = (mtb + mt) * 16 + krow * 4 + r;
                float v0 = fmaxf(c1[mt][r]     + b1[j0],     0.f);
                float v1 = fmaxf(c1[mt][r + 1] + b1[j0 + 1], 0.f);
                *(unsigned int*)(&relay[pair][col][j0]) = cvt_pk_bf16(v0, v1);
            }
        }
        __syncthreads();   // both halves of relay complete

        // ---- L2: full-K read, own 3 mt ----
        f32x4 c2[3] = {};
        __builtin_amdgcn_s_setprio(1);
#pragma unroll
        for (int kt = 0; kt < 3; kt++) {
            short8 b = *(const short8*)(&relay[pair][col][kt * 32 + krow * 8]);
#pragma unroll
            for (int mt = 0; mt < 3; mt++)
                c2[mt] = __builtin_amdgcn_mfma_f32_16x16x32_bf16(W2s[((mtb + mt) * 3 + kt) * 64 + l], b, c2[mt], 0, 0, 0);
        }
        __builtin_amdgcn_s_setprio(0);

        // ---- msg (bias+relu); inject carry at col0 ----
        float s[12];
#pragma unroll
        for (int mt = 0; mt < 3; mt++)
#pragma unroll
            for (int r = 0; r < 4; r++) {
                int j = (mtb + mt) * 16 + krow * 4 + r;
                float v = fmaxf(c2[mt][r] + b2[j], 0.f);
                s[mt * 4 + r] = v + ((col == 0) ? carry[mt * 4 + r] : 0.f);
            }
        // ---- segmented inclusive scan over col ----
        unsigned fl = (m16 >> col) & 1u;
        seg_step<0x111>(s, fl);
        seg_step<0x112>(s, fl);
        seg_step<0x114>(s, fl);
        seg_step<0x118>(s, fl);
        // ---- emission (wave's 48 dims only) ----
        bool is_end = (col == 15) || ((m16 >> (col + 1)) & 1u);
        if (active && is_end && !((col == 15) && continuing)) {
            unsigned lowmask = (2u << col) - 1u;
            bool first_seg = (__popc(m16 & lowmask) == 1);
            bool use_atomic = (first_seg && head) || ((col == 15) && !hasN);
            float* base = r2agg + (size_t)did * 96 + krow * 4;
            if (use_atomic) {
#pragma unroll
                for (int mt = 0; mt < 3; mt++)
#pragma unroll
                    for (int r = 0; r < 4; r++)
                        atomicAdd(base + (mtb + mt) * 16 + r, s[mt * 4 + r]);
            } else {
#pragma unroll
                for (int mt = 0; mt < 3; mt++)
                    *(float4*)(base + (mtb + mt) * 16) = make_float4(s[mt * 4], s[mt * 4 + 1],
                                                                    s[mt * 4 + 2], s[mt * 4 + 3]);
            }
        }
        // ---- carry update (wave-uniform) ----
        if (continuing) {
            head = head && (m16 == 1u);
#pragma unroll
            for (int q = 0; q < 12; q++) carry[q] = ror_prev(s[q]);
        } else {
            head = false;
#pragma unroll
            for (int q = 0; q < 12; q++) carry[q] = 0.f;
        }
        __syncthreads();   // relay consumed; safe to overwrite next tile
        sid = sidN; did = didN;
    }
}

// ---------------------------------------------------------------------------
// Node phase: 4 waves x 64 shared nodes; wave w owns d-range [32w,32w+32)
// of all gates (and out rows [16w,16w+16)). Weights read once per wave with
// x4 B-frag reuse. 3 barriers, no weight staging.
__global__ __launch_bounds__(256) void k_node_mfma(
    const float* __restrict__ inp,      // [N][64]
    const float* __restrict__ r2agg,    // [NPAD][96]
    const int* __restrict__ row_off,    // [N+1]
    float* __restrict__ h,              // [N][128] fp32 in/out
    unsigned short* __restrict__ hbf,   // [N][128] bf16 in/out
    const short8* __restrict__ WbigA,   // [16][9] tiles
    const short8* __restrict__ WniA,    // [8][5]
    const short8* __restrict__ WnhA,    // [8][4]
    const short8* __restrict__ WoutA,   // [4][4]
    const float* __restrict__ vb3,
    const float* __restrict__ bsum,
    const float* __restrict__ b_hh,
    const float* __restrict__ b_out,
    float* __restrict__ out, int iter)
{
    __shared__ __attribute__((aligned(16))) unsigned short X[4][16][XROW]; // 37888 B
    __shared__ float degs[64];
    int t = threadIdx.x;
    int w = t >> 6, l = t & 63;
    int nb = blockIdx.x * 64;
    int col = l & 15, krow = l >> 4;

    // ---- stage X = [inp(64) | r2(96) | h(128)] bf16 + degs ----
    for (int idx = t; idx < 64 * 32; idx += 256) {
        int i = idx >> 5, kk = (idx & 31) << 1;
        int n = nb + i;
        float2 v = make_float2(0.f, 0.f);
        if (n < N_NODES) v = *(const float2*)(inp + (size_t)n * 64 + kk);
        *(unsigned int*)(&X[i >> 4][i & 15][kk]) = cvt_pk_bf16(v.x, v.y);
    }
    for (int idx = t; idx < 64 * 48; idx += 256) {      // r2 node-major pairs
        int i = (int)((unsigned)idx / 48u), kp = idx - i * 48;
        int n = nb + i;
        float2 v = make_float2(0.f, 0.f);
        if (n < N_NODES) v = *(const float2*)(r2agg + (size_t)n * 96 + kp * 2);
        *(unsigned int*)(&X[i >> 4][i & 15][64 + kp * 2]) = cvt_pk_bf16(v.x, v.y);
    }
    for (int idx = t; idx < 64 * 16; idx += 256) {
        int i = idx >> 4, c = idx & 15;
        int n = nb + i;
        uint4 v = make_uint4(0, 0, 0, 0);
        if (n < N_NODES) v = ((const uint4*)(hbf + (size_t)n * 128))[c];
        *(uint4*)(&X[i >> 4][i & 15][160 + c * 8]) = v;
    }
    if (t < 64) {
        int n = nb + t;
        degs[t] = (n < N_NODES) ? (float)(row_off[n + 1] - row_off[n]) : 0.f;
    }
    __syncthreads();

    // ---- GEMMs: wave w computes d in [32w, 32w+32) ----
    int mts[4] = {2 * w, 2 * w + 1, 8 + 2 * w, 9 + 2 * w};   // r lo/hi, z lo/hi
    f32x4 cg[4][4] = {};
#pragma unroll 3
    for (int kt = 0; kt < 9; kt++) {
        short8 b[4];
#pragma unroll
        for (int bf = 0; bf < 4; bf++) b[bf] = *(const short8*)(&X[bf][col][kt * 32 + krow * 8]);
#pragma unroll
        for (int mi = 0; mi < 4; mi++) {
            short8 a = WbigA[(mts[mi] * 9 + kt) * 64 + l];
#pragma unroll
            for (int bf = 0; bf < 4; bf++)
                cg[mi][bf] = __builtin_amdgcn_mfma_f32_16x16x32_bf16(a, b[bf], cg[mi][bf], 0, 0, 0);
        }
    }
    f32x4 ci[2][4] = {};
#pragma unroll
    for (int kt = 0; kt < 5; kt++) {
        short8 b[4];
#pragma unroll
        for (int bf = 0; bf < 4; bf++) b[bf] = *(const short8*)(&X[bf][col][kt * 32 + krow * 8]);
#pragma unroll
        for (int mi = 0; mi < 2; mi++) {
            short8 a = WniA[((2 * w + mi) * 5 + kt) * 64 + l];
#pragma unroll
            for (int bf = 0; bf < 4; bf++)
                ci[mi][bf] = __builtin_amdgcn_mfma_f32_16x16x32_bf16(a, b[bf], ci[mi][bf], 0, 0, 0);
        }
    }
    f32x4 ch[2][4] = {};
#pragma unroll
    for (int kt = 0; kt < 4; kt++) {
        short8 b[4];
#pragma unroll
        for (int bf = 0; bf < 4; bf++) b[bf] = *(const short8*)(&X[bf][col][160 + kt * 32 + krow * 8]);
#pragma unroll
        for (int mi = 0; mi < 2; mi++) {
            short8 a = WnhA[((2 * w + mi) * 4 + kt) * 64 + l];
#pragma unroll
            for (int bf = 0; bf < 4; bf++)
                ch[mi][bf] = __builtin_amdgcn_mfma_f32_16x16x32_bf16(a, b[bf], ch[mi][bf], 0, 0, 0);
        }
    }
    __syncthreads();   // all reads of old-h in X complete

    // ---- GRU epilogue: wave w writes d-range [32w,32w+32) for all 64 nodes ----
#pragma unroll
    for (int mi = 0; mi < 2; mi++) {
        int d0 = w * 32 + mi * 16 + krow * 4;
        float4 bsr = *(const float4*)(bsum + d0);
        float4 bsz = *(const float4*)(bsum + 128 + d0);
        float4 bsn = *(const float4*)(bsum + 256 + d0);
        float4 vbr = *(const float4*)(vb3 + d0);
        float4 vbz = *(const float4*)(vb3 + 128 + d0);
        float4 vbn = *(const float4*)(vb3 + 256 + d0);
        float4 bhn = *(const float4*)(b_hh + 256 + d0);
        float bsrv[4] = {bsr.x, bsr.y, bsr.z, bsr.w};
        float bszv[4] = {bsz.x, bsz.y, bsz.z, bsz.w};
        float bsnv[4] = {bsn.x, bsn.y, bsn.z, bsn.w};
        float vbrv[4] = {vbr.x, vbr.y, vbr.z, vbr.w};
        float vbzv[4] = {vbz.x, vbz.y, vbz.z, vbz.w};
        float vbnv[4] = {vbn.x, vbn.y, vbn.z, vbn.w};
        float bhnv[4] = {bhn.x, bhn.y, bhn.z, bhn.w};
#pragma unroll
        for (int bf = 0; bf < 4; bf++) {
            int n = nb + bf * 16 + col;
            bool valid = (n < N_NODES);
            float deg = degs[bf * 16 + col];
            float4 ho = make_float4(0.f, 0.f, 0.f, 0.f);
            if (valid) ho = *(const float4*)(h + (size_t)n * 128 + d0);
            float hov[4] = {ho.x, ho.y, ho.z, ho.w};
            float hv[4];
#pragma unroll
            for (int r = 0; r < 4; r++) {
                float rp = cg[mi][bf][r]     + bsrv[r] + deg * vbrv[r];
                float zp = cg[2 + mi][bf][r] + bszv[r] + deg * vbzv[r];
                float ip = ci[mi][bf][r]     + bsnv[r] + deg * vbnv[r];
                float hp = ch[mi][bf][r]     + bhnv[r];
                float rg = 1.f / (1.f + __expf(-rp));
                float zg = 1.f / (1.f + __expf(-zp));
                float ng = fast_tanh(ip + rg * hp);
                hv[r] = (1.f - zg) * ng + zg * hov[r];
            }
            if (valid)
                *(float4*)(h + (size_t)n * 128 + d0) = make_float4(hv[0], hv[1], hv[2], hv[3]);
            *(unsigned int*)(&X[bf][col][160 + d0])     = cvt_pk_bf16(hv[0], hv[1]);
            *(unsigned int*)(&X[bf][col][160 + d0 + 2]) = cvt_pk_bf16(hv[2], hv[3]);
        }
    }
    __syncthreads();   // h_new complete in X

    // ---- out projection: wave w computes rows [16w,16w+16) ----
    f32x4 co[4] = {};
#pragma unroll
    for (int kt = 0; kt < 4; kt++) {
        short8 a = WoutA[(w * 4 + kt) * 64 + l];
#pragma unroll
        for (int bf = 0; bf < 4; bf++) {
            short8 b = *(const short8*)(&X[bf][col][160 + kt * 32 + krow * 8]);
            co[bf] = __builtin_amdgcn_mfma_f32_16x16x32_bf16(a, b, co[bf], 0, 0, 0);
        }
    }
    {
        int o0 = w * 16 + krow * 4;
        float4 bo = *(const float4*)(b_out + o0);
#pragma unroll
        for (int bf = 0; bf < 4; bf++) {
            int n = nb + bf * 16 + col;
            if (n < N_NODES) {
                float* op = out + (size_t)iter * N_NODES * 64 + (size_t)n * 64 + o0;
                *(float4*)op = make_float4(co[bf][0] + bo.x, co[bf][1] + bo.y,
                                           co[bf][2] + bo.z, co[bf][3] + bo.w);
            }
        }
    }

    // ---- hbf writeback ----
    for (int idx = t; idx < 64 * 16; idx += 256) {
        int i = idx >> 4, c = idx & 15;
        int n2 = nb + i;
        if (n2 < N_NODES)
            ((uint4*)(hbf + (size_t)n2 * 128))[c] = *(const uint4*)(&X[i >> 4][i & 15][160 + c * 8]);
    }
}

// ---------------------------------------------------------------------------
extern "C" void kernel_launch(void* const* d_in, const int* in_sizes, int n_in,
                              void* d_out, int out_size, void* d_ws, size_t ws_size,
                              hipStream_t stream)
{
    const float* inp   = (const float*)d_in[0];
    const int*   src   = (const int*)d_in[1];
    const int*   dst   = (const int*)d_in[2];
    const float* W1    = (const float*)d_in[3];
    const float* b1    = (const float*)d_in[4];
    const float* W2    = (const float*)d_in[5];
    const float* b2    = (const float*)d_in[6];
    const float* W3    = (const float*)d_in[7];
    const float* b3    = (const float*)d_in[8];
    const float* W_ih  = (const float*)d_in[9];
    const float* W_hh  = (const float*)d_in[10];
    const float* b_ih  = (const float*)d_in[11];
    const float* b_hh  = (const float*)d_in[12];
    const float* W_out = (const float*)d_in[13];
    const float* b_out = (const float*)d_in[14];
    float* out = (float*)d_out;

    char* ws = (char*)d_ws;
    size_t off = 0;
    auto alloc = [&](size_t bytes) -> void* {
        void* p = ws + off;
        off += (bytes + 255) & ~(size_t)255;
        return p;
    };
    float* h       = (float*)alloc((size_t)N_NODES * 128 * 4);
    unsigned short* hbf = (unsigned short*)alloc((size_t)N_NODES * 128 * 2);
    float* r2agg   = (float*)alloc((size_t)NPAD * 96 * 4);
    float* Wbig    = (float*)alloc((size_t)256 * 288 * 4);
    float* Wni     = (float*)alloc((size_t)128 * 160 * 4);
    float* vb3     = (float*)alloc((size_t)384 * 4);
    float* bsum    = (float*)alloc((size_t)384 * 4);
    unsigned short* W1A   = (unsigned short*)alloc((size_t)6 * 8 * 512 * 2);
    unsigned short* W2A   = (unsigned short*)alloc((size_t)6 * 3 * 512 * 2);
    unsigned short* WbigA = (unsigned short*)alloc((size_t)16 * 9 * 512 * 2);
    unsigned short* WniA  = (unsigned short*)alloc((size_t)8 * 5 * 512 * 2);
    unsigned short* WnhA  = (unsigned short*)alloc((size_t)8 * 4 * 512 * 2);
    unsigned short* WoutA = (unsigned short*)alloc((size_t)4 * 4 * 512 * 2);
    int*   counts  = (int*)alloc((size_t)N_NODES * 4);
    int*   cursor  = (int*)alloc((size_t)N_NODES * 4);
    int*   row_off = (int*)alloc((size_t)(N_NODES + 1) * 4);
    int*   perm_src= (int*)alloc((size_t)N_EDGES * 4);
    int*   perm_dst= (int*)alloc((size_t)N_EDGES * 4);

    // ---- one-time preprocessing ----
    hipMemsetAsync(h, 0, (size_t)N_NODES * 128 * 4, stream);
    hipMemsetAsync(hbf, 0, (size_t)N_NODES * 128 * 2, stream);
    hipMemsetAsync(counts, 0, (size_t)N_NODES * 4, stream);
    hipMemsetAsync(cursor, 0, (size_t)N_NODES * 4, stream);

    k_build_wbig<<<(256 * 288 + 255) / 256, 256, 0, stream>>>(W_ih, W3, W_hh, Wbig);
    k_build_wni<<<(128 * 160 + 255) / 256, 256, 0, stream>>>(W_ih, W3, Wni);
    k_vb3<<<2, 256, 0, stream>>>(W_ih, b3, vb3);
    k_bsum<<<2, 256, 0, stream>>>(b_ih, b_hh, bsum);

    k_pack2<<<(6 * 8 * 512 + 255) / 256, 256, 0, stream>>>(W1, W1A, 6, 8, 256, 0);
    k_pack2<<<(6 * 3 * 512 + 255) / 256, 256, 0, stream>>>(W2, W2A, 6, 3, 96, 0);
    k_pack2<<<(16 * 9 * 512 + 255) / 256, 256, 0, stream>>>(Wbig, WbigA, 16, 9, 288, 0);
    k_pack2<<<(8 * 5 * 512 + 255) / 256, 256, 0, stream>>>(Wni, WniA, 8, 5, 160, 0);
    k_pack2<<<(8 * 4 * 512 + 255) / 256, 256, 0, stream>>>(W_hh, WnhA, 8, 4, 128, 256);
    k_pack2<<<(4 * 4 * 512 + 255) / 256, 256, 0, stream>>>(W_out, WoutA, 4, 4, 128, 0);

    k_hist<<<(N_EDGES + 255) / 256, 256, 0, stream>>>(dst, counts);
    k_scan<<<1, 1024, 0, stream>>>(counts, row_off);
    k_permute<<<(N_EDGES + 255) / 256, 256, 0, stream>>>(src, dst, row_off, cursor,
                                                         perm_src, perm_dst);

    // ---- iterations ----
    for (int it = 0; it < N_ITERS; ++it) {
        hipMemsetAsync(r2agg, 0, (size_t)NPAD * 96 * 4, stream);
        k_edge_fused<<<512, 256, 0, stream>>>(hbf, perm_src, perm_dst,
                                              (const short8*)W1A, (const short8*)W2A,
                                              b1, b2, r2agg);
        k_node_mfma<<<(N_NODES + 63) / 64, 256, 0, stream>>>(inp, r2agg, row_off, h, hbf,
                                                     (const short8*)WbigA, (const short8*)WniA,
                                                     (const short8*)WnhA, (const short8*)WoutA,
                                                     vb3, bsum, b_hh, b_out, out, it);
    }
}

// Round 18
// 1659.661 us; speedup vs baseline: 2.1314x; 1.0262x over previous
//
#include <hip/hip_runtime.h>

#define N_NODES 50000
#define N_EDGES 800000
#define N_ITERS 7
#define NPAD 50048
#define NT16 (N_EDGES / 16)   // 50000 16-edge tiles
#define TOTP 1024             // 512 blocks x 2 pairs
#define TPP ((NT16 + TOTP - 1) / TOTP)   // 49 tiles per pair

typedef __attribute__((ext_vector_type(8))) short short8;
typedef __attribute__((ext_vector_type(4))) float f32x4;

#define AROW 104   // pair-shared relay row: 96 bf16 + 8 pad
#define XROW 296   // X row: 288 bf16 + 8 pad

static __device__ __forceinline__ unsigned short f2bf(float f) {
    unsigned int u = __float_as_uint(f);
    unsigned int r = (u + 0x7fffu + ((u >> 16) & 1u)) >> 16;
    return (unsigned short)r;
}
static __device__ __forceinline__ float bf2f(unsigned short u) {
    return __uint_as_float(((unsigned int)u) << 16);
}
// pack two f32 -> 2x bf16 (RNE), lo in bits [15:0]
static __device__ __forceinline__ unsigned cvt_pk_bf16(float lo, float hi) {
    unsigned r;
    asm("v_cvt_pk_bf16_f32 %0, %1, %2" : "=v"(r) : "v"(lo), "v"(hi));
    return r;
}
static __device__ __forceinline__ float fast_tanh(float x) {
    float xc = fminf(fmaxf(x, -15.f), 15.f);
    float t = __expf(2.f * xc);
    return (t - 1.f) / (t + 1.f);
}
// row_ror:1 (0x121): lane i <- lane (i-1) mod 16, so col0 receives col15.
static __device__ __forceinline__ float ror_prev(float x) {
    return __int_as_float(__builtin_amdgcn_update_dpp(0, __float_as_int(x), 0x121, 0xf, 0xf, true));
}

// one segmented-scan step over the 16-lane row group (row_shr:CTRL&15, bound_ctrl=1)
template <int CTRL, int N>
static __device__ __forceinline__ void seg_step(float (&s)[N], unsigned& fl) {
    unsigned fv = (unsigned)__builtin_amdgcn_update_dpp(0, (int)fl, CTRL, 0xf, 0xf, true);
    float g = fl ? 0.f : 1.f;
#pragma unroll
    for (int q = 0; q < N; q++) {
        int sv = __builtin_amdgcn_update_dpp(0, __float_as_int(s[q]), CTRL, 0xf, 0xf, true);
        s[q] += __int_as_float(sv) * g;
    }
    fl |= fv;
}

// ---------------------------------------------------------------------------
// Wbig [256][288]: rows = r,z gates; cols = [W_ih[:, :64] | W_ih[:,64:]@W3 | W_hh]
__global__ __launch_bounds__(256) void k_build_wbig(const float* __restrict__ W_ih,
                                                    const float* __restrict__ W3,
                                                    const float* __restrict__ W_hh,
                                                    float* __restrict__ Wbig) {
    int idx = blockIdx.x * 256 + threadIdx.x;
    if (idx >= 256 * 288) return;
    int g = idx / 288, k = idx - g * 288;
    float v;
    if (k < 64) v = W_ih[g * 192 + k];
    else if (k < 160) {
        int kk = k - 64; float s = 0.f;
        for (int j = 0; j < 128; j++) s += W_ih[g * 192 + 64 + j] * W3[j * 96 + kk];
        v = s;
    } else v = W_hh[g * 128 + (k - 160)];
    Wbig[idx] = v;
}

// Wni [128][160]: n-gate input part (W_ih rows 256..383, with W3 fold)
__global__ __launch_bounds__(256) void k_build_wni(const float* __restrict__ W_ih,
                                                   const float* __restrict__ W3,
                                                   float* __restrict__ Wni) {
    int idx = blockIdx.x * 256 + threadIdx.x;
    if (idx >= 128 * 160) return;
    int g = idx / 160, k = idx - g * 160;
    int gg = 256 + g;
    float v;
    if (k < 64) v = W_ih[gg * 192 + k];
    else {
        int kk = k - 64; float s = 0.f;
        for (int j = 0; j < 128; j++) s += W_ih[gg * 192 + 64 + j] * W3[j * 96 + kk];
        v = s;
    }
    Wni[idx] = v;
}

__global__ __launch_bounds__(256) void k_vb3(const float* __restrict__ W_ih,
                                             const float* __restrict__ b3,
                                             float* __restrict__ vb3) {
    int g = blockIdx.x * 256 + threadIdx.x;
    if (g >= 384) return;
    float s = 0.f;
    for (int j = 0; j < 128; j++) s += W_ih[g * 192 + 64 + j] * b3[j];
    vb3[g] = s;
}

__global__ __launch_bounds__(256) void k_bsum(const float* __restrict__ b_ih,
                                              const float* __restrict__ b_hh,
                                              float* __restrict__ bsum) {
    int d = blockIdx.x * 256 + threadIdx.x;
    if (d >= 384) return;
    bsum[d] = b_ih[d] + (d < 256 ? b_hh[d] : 0.f);
}

// ---------------------------------------------------------------------------
// Pack: src fp32 (ld), element (row0+j, k) -> A-frags [Mt][KT][64][8]
__global__ __launch_bounds__(256) void k_pack2(const float* __restrict__ src,
                                               unsigned short* __restrict__ out,
                                               int Mt, int KT, int ld, int row0) {
    int idx = blockIdx.x * 256 + threadIdx.x;
    if (idx >= Mt * KT * 512) return;
    int jj = idx & 7;
    int l  = (idx >> 3) & 63;
    int tile = idx >> 9;
    int kt = tile % KT;
    int mt = tile / KT;
    int j = row0 + mt * 16 + (l & 15);
    int k = kt * 32 + (l >> 4) * 8 + jj;
    out[idx] = f2bf(src[(size_t)j * ld + k]);
}

// ---------------------------------------------------------------------------
// CSR build (once; ids fixed across iterations)
__global__ __launch_bounds__(256) void k_hist(const int* __restrict__ dst,
                                              int* __restrict__ counts) {
    int e = blockIdx.x * 256 + threadIdx.x;
    if (e < N_EDGES) atomicAdd(&counts[dst[e]], 1);
}

__global__ __launch_bounds__(1024) void k_scan(const int* __restrict__ counts,
                                               int* __restrict__ row_off) {
    __shared__ int sh[1024];
    int t = threadIdx.x;
    const int STR = 49;
    int base = t * STR;
    int s = 0;
    for (int i = 0; i < STR; i++) {
        int n = base + i;
        if (n < N_NODES) s += counts[n];
    }
    sh[t] = s;
    __syncthreads();
    for (int off = 1; off < 1024; off <<= 1) {
        int v = (t >= off) ? sh[t - off] : 0;
        __syncthreads();
        sh[t] += v;
        __syncthreads();
    }
    int run = (t == 0) ? 0 : sh[t - 1];
    for (int i = 0; i < STR; i++) {
        int n = base + i;
        if (n < N_NODES) { row_off[n] = run; run += counts[n]; }
    }
    if (t == 1023) row_off[N_NODES] = run;
}

__global__ __launch_bounds__(256) void k_permute(const int* __restrict__ src,
                                                 const int* __restrict__ dst,
                                                 const int* __restrict__ row_off,
                                                 int* __restrict__ cursor,
                                                 int* __restrict__ perm_src,
                                                 int* __restrict__ perm_dst) {
    int e = blockIdx.x * 256 + threadIdx.x;
    if (e >= N_EDGES) return;
    int d = dst[e];
    int pos = row_off[d] + atomicAdd(&cursor[d], 1);
    perm_src[pos] = src[e];
    perm_dst[pos] = d;
}

// ---------------------------------------------------------------------------
// Fused edge MLP + aggregation, SPLIT-M wave pairs (<=128 VGPR -> 2 blocks/CU,
// confirmed R17: 88 VGPR @ 22% occ). R18: dual fragment prefetch — BOTH src
// and dst halves of tile t+1 are loaded right after the mid-tile barrier,
// covered by L2+scan+barrier; L1 runs 24 MFMAs with zero mid-tile loads
// (R17 loaded dst mid-tile with only ~60cyc of MFMA cover). ~+32 VGPR -> ~120.
__global__ __launch_bounds__(256) void k_edge_fused(
    const unsigned short* __restrict__ hbf,   // [N][128] bf16
    const int* __restrict__ perm_src, const int* __restrict__ perm_dst,
    const short8* __restrict__ W1Ag,          // [6*8*64] frags
    const short8* __restrict__ W2Ag,          // [6*3*64] frags
    const float* __restrict__ b1,
    const float* __restrict__ b2,
    float* __restrict__ r2agg)                // [NPAD][96]
{
    __shared__ __attribute__((aligned(16))) short8 W1s[6 * 8 * 64];      // 49152 B
    __shared__ __attribute__((aligned(16))) short8 W2s[6 * 3 * 64];      // 18432 B
    __shared__ __attribute__((aligned(16))) unsigned short relay[2][16][AROW]; // 6656 B

    int t = threadIdx.x;
    int w = t >> 6, l = t & 63;
    int col = l & 15, krow = l >> 4;
    int pair = w >> 1;          // 0..1
    int u = w & 1;              // M-half: neurons [48u, 48u+48)
    int mtb = 3 * u;            // global mt base

    for (int i = t; i < 6 * 8 * 64; i += 256) W1s[i] = W1Ag[i];
    for (int i = t; i < 6 * 3 * 64; i += 256) W2s[i] = W2Ag[i];
    __syncthreads();

    int pidx = blockIdx.x * 2 + pair;
    int tlo = pidx * TPP;
    int thi = tlo + TPP; if (thi > NT16) thi = NT16;
    int ntiles = thi - tlo; if (ntiles < 0) ntiles = 0;

    float carry[12];
#pragma unroll
    for (int q = 0; q < 12; q++) carry[q] = 0.f;
    bool head = true;

    // preload first tile ids + BOTH fragment halves (clamped for inactive)
    int te0 = tlo; if (te0 >= NT16) te0 = NT16 - 1;
    int sid, did;
    { int e = te0 * 16 + col; sid = perm_src[e]; did = perm_dst[e]; }
    short8 frS[4], frD[4];
    {
        const unsigned short* sr = hbf + (size_t)sid * 128 + krow * 8;
        const unsigned short* dr = hbf + (size_t)did * 128 + krow * 8;
#pragma unroll
        for (int kt = 0; kt < 4; kt++) frS[kt] = *(const short8*)(sr + kt * 32);
#pragma unroll
        for (int kt = 0; kt < 4; kt++) frD[kt] = *(const short8*)(dr + kt * 32);
    }

    for (int tt = 0; tt < TPP; ++tt) {
        bool active = (tt < ntiles);
        bool hasN = (tt + 1 < ntiles);
        int teN = tlo + tt + 1; if (teN >= NT16) teN = NT16 - 1;
        int sidN, didN;
        { int e = teN * 16 + col; sidN = perm_src[e]; didN = perm_dst[e]; }

        int dp = __shfl_up(did, 1);
        unsigned m16 = (unsigned)__ballot((col == 0) || (did != dp)) & 0xFFFFu;
        bool continuing = hasN && (__shfl(did, 15) == __shfl(didN, 0));

        // ---- L1: 3 mt x 8 kt, both halves prefetched (no mid-tile loads) ----
        f32x4 c1[3] = {};
        __builtin_amdgcn_s_setprio(1);
#pragma unroll
        for (int kt = 0; kt < 4; kt++) {
#pragma unroll
            for (int mt = 0; mt < 3; mt++)
                c1[mt] = __builtin_amdgcn_mfma_f32_16x16x32_bf16(W1s[((mtb + mt) * 8 + kt) * 64 + l], frS[kt], c1[mt], 0, 0, 0);
        }
#pragma unroll
        for (int kt = 0; kt < 4; kt++) {
#pragma unroll
            for (int mt = 0; mt < 3; mt++)
                c1[mt] = __builtin_amdgcn_mfma_f32_16x16x32_bf16(W1s[((mtb + mt) * 8 + 4 + kt) * 64 + l], frD[kt], c1[mt], 0, 0, 0);
        }
        __builtin_amdgcn_s_setprio(0);

        // ---- a1 epilogue: wave writes its 48 dims of the pair relay ----
#pragma unroll
        for (int mt = 0; mt < 3; mt++) {
#pragma unroll
            for (int r = 0; r < 4; r += 2) {
                int j0 = (mtb + mt) * 16 + krow * 4 + r;
                float v0 = fmaxf(c1[mt][r]     + b1[j0],     0.f);
                float v1 = fmaxf(c1[mt][r + 1] + b1[j0 + 1], 0.f);
                *(unsigned int*)(&relay[pair][col][j0]) = cvt_pk_bf16(v0, v1);
            }
        }
        __syncthreads();   // both halves of relay complete

        // ---- prefetch BOTH halves of next tile (covered by L2+scan+barrier) ----
        {
            const unsigned short* sr = hbf + (size_t)sidN * 128 + krow * 8;
            const unsigned short* dr = hbf + (size_t)didN * 128 + krow * 8;
#pragma unroll
            for (int kt = 0; kt < 4; kt++) frS[kt] = *(const short8*)(sr + kt * 32);
#pragma unroll
            for (int kt = 0; kt < 4; kt++) frD[kt] = *(const short8*)(dr + kt * 32);
        }

        // ---- L2: full-K read, own 3 mt ----
        f32x4 c2[3] = {};
        __builtin_amdgcn_s_setprio(1);
#pragma unroll
        for (int kt = 0; kt < 3; kt++) {
            short8 b = *(const short8*)(&relay[pair][col][kt * 32 + krow * 8]);
#pragma unroll
            for (int mt = 0; mt < 3; mt++)
                c2[mt] = __builtin_amdgcn_mfma_f32_16x16x32_bf16(W2s[((mtb + mt) * 3 + kt) * 64 + l], b, c2[mt], 0, 0, 0);
        }
        __builtin_amdgcn_s_setprio(0);

        // ---- msg (bias+relu); inject carry at col0 ----
        float s[12];
#pragma unroll
        for (int mt = 0; mt < 3; mt++)
#pragma unroll
            for (int r = 0; r < 4; r++) {
                int j = (mtb + mt) * 16 + krow * 4 + r;
                float v = fmaxf(c2[mt][r] + b2[j], 0.f);
                s[mt * 4 + r] = v + ((col == 0) ? carry[mt * 4 + r] : 0.f);
            }
        // ---- segmented inclusive scan over col ----
        unsigned fl = (m16 >> col) & 1u;
        seg_step<0x111>(s, fl);
        seg_step<0x112>(s, fl);
        seg_step<0x114>(s, fl);
        seg_step<0x118>(s, fl);
        // ---- emission (wave's 48 dims only) ----
        bool is_end = (col == 15) || ((m16 >> (col + 1)) & 1u);
        if (active && is_end && !((col == 15) && continuing)) {
            unsigned lowmask = (2u << col) - 1u;
            bool first_seg = (__popc(m16 & lowmask) == 1);
            bool use_atomic = (first_seg && head) || ((col == 15) && !hasN);
            float* base = r2agg + (size_t)did * 96 + krow * 4;
            if (use_atomic) {
#pragma unroll
                for (int mt = 0; mt < 3; mt++)
#pragma unroll
                    for (int r = 0; r < 4; r++)
                        atomicAdd(base + (mtb + mt) * 16 + r, s[mt * 4 + r]);
            } else {
#pragma unroll
                for (int mt = 0; mt < 3; mt++)
                    *(float4*)(base + (mtb + mt) * 16) = make_float4(s[mt * 4], s[mt * 4 + 1],
                                                                    s[mt * 4 + 2], s[mt * 4 + 3]);
            }
        }
        // ---- carry update (wave-uniform) ----
        if (continuing) {
            head = head && (m16 == 1u);
#pragma unroll
            for (int q = 0; q < 12; q++) carry[q] = ror_prev(s[q]);
        } else {
            head = false;
#pragma unroll
            for (int q = 0; q < 12; q++) carry[q] = 0.f;
        }
        __syncthreads();   // relay consumed; safe to overwrite next tile
        sid = sidN; did = didN;
    }
}

// ---------------------------------------------------------------------------
// Node phase: 4 waves x 64 shared nodes; wave w owns d-range [32w,32w+32)
// of all gates (and out rows [16w,16w+16)). Weights read once per wave with
// x4 B-frag reuse. 3 barriers, no weight staging.
__global__ __launch_bounds__(256) void k_node_mfma(
    const float* __restrict__ inp,      // [N][64]
    const float* __restrict__ r2agg,    // [NPAD][96]
    const int* __restrict__ row_off,    // [N+1]
    float* __restrict__ h,              // [N][128] fp32 in/out
    unsigned short* __restrict__ hbf,   // [N][128] bf16 in/out
    const short8* __restrict__ WbigA,   // [16][9] tiles
    const short8* __restrict__ WniA,    // [8][5]
    const short8* __restrict__ WnhA,    // [8][4]
    const short8* __restrict__ WoutA,   // [4][4]
    const float* __restrict__ vb3,
    const float* __restrict__ bsum,
    const float* __restrict__ b_hh,
    const float* __restrict__ b_out,
    float* __restrict__ out, int iter)
{
    __shared__ __attribute__((aligned(16))) unsigned short X[4][16][XROW]; // 37888 B
    __shared__ float degs[64];
    int t = threadIdx.x;
    int w = t >> 6, l = t & 63;
    int nb = blockIdx.x * 64;
    int col = l & 15, krow = l >> 4;

    // ---- stage X = [inp(64) | r2(96) | h(128)] bf16 + degs ----
    for (int idx = t; idx < 64 * 32; idx += 256) {
        int i = idx >> 5, kk = (idx & 31) << 1;
        int n = nb + i;
        float2 v = make_float2(0.f, 0.f);
        if (n < N_NODES) v = *(const float2*)(inp + (size_t)n * 64 + kk);
        *(unsigned int*)(&X[i >> 4][i & 15][kk]) = cvt_pk_bf16(v.x, v.y);
    }
    for (int idx = t; idx < 64 * 48; idx += 256) {      // r2 node-major pairs
        int i = (int)((unsigned)idx / 48u), kp = idx - i * 48;
        int n = nb + i;
        float2 v = make_float2(0.f, 0.f);
        if (n < N_NODES) v = *(const float2*)(r2agg + (size_t)n * 96 + kp * 2);
        *(unsigned int*)(&X[i >> 4][i & 15][64 + kp * 2]) = cvt_pk_bf16(v.x, v.y);
    }
    for (int idx = t; idx < 64 * 16; idx += 256) {
        int i = idx >> 4, c = idx & 15;
        int n = nb + i;
        uint4 v = make_uint4(0, 0, 0, 0);
        if (n < N_NODES) v = ((const uint4*)(hbf + (size_t)n * 128))[c];
        *(uint4*)(&X[i >> 4][i & 15][160 + c * 8]) = v;
    }
    if (t < 64) {
        int n = nb + t;
        degs[t] = (n < N_NODES) ? (float)(row_off[n + 1] - row_off[n]) : 0.f;
    }
    __syncthreads();

    // ---- GEMMs: wave w computes d in [32w, 32w+32) ----
    int mts[4] = {2 * w, 2 * w + 1, 8 + 2 * w, 9 + 2 * w};   // r lo/hi, z lo/hi
    f32x4 cg[4][4] = {};
#pragma unroll 3
    for (int kt = 0; kt < 9; kt++) {
        short8 b[4];
#pragma unroll
        for (int bf = 0; bf < 4; bf++) b[bf] = *(const short8*)(&X[bf][col][kt * 32 + krow * 8]);
#pragma unroll
        for (int mi = 0; mi < 4; mi++) {
            short8 a = WbigA[(mts[mi] * 9 + kt) * 64 + l];
#pragma unroll
            for (int bf = 0; bf < 4; bf++)
                cg[mi][bf] = __builtin_amdgcn_mfma_f32_16x16x32_bf16(a, b[bf], cg[mi][bf], 0, 0, 0);
        }
    }
    f32x4 ci[2][4] = {};
#pragma unroll
    for (int kt = 0; kt < 5; kt++) {
        short8 b[4];
#pragma unroll
        for (int bf = 0; bf < 4; bf++) b[bf] = *(const short8*)(&X[bf][col][kt * 32 + krow * 8]);
#pragma unroll
        for (int mi = 0; mi < 2; mi++) {
            short8 a = WniA[((2 * w + mi) * 5 + kt) * 64 + l];
#pragma unroll
            for (int bf = 0; bf < 4; bf++)
                ci[mi][bf] = __builtin_amdgcn_mfma_f32_16x16x32_bf16(a, b[bf], ci[mi][bf], 0, 0, 0);
        }
    }
    f32x4 ch[2][4] = {};
#pragma unroll
    for (int kt = 0; kt < 4; kt++) {
        short8 b[4];
#pragma unroll
        for (int bf = 0; bf < 4; bf++) b[bf] = *(const short8*)(&X[bf][col][160 + kt * 32 + krow * 8]);
#pragma unroll
        for (int mi = 0; mi < 2; mi++) {
            short8 a = WnhA[((2 * w + mi) * 4 + kt) * 64 + l];
#pragma unroll
            for (int bf = 0; bf < 4; bf++)
                ch[mi][bf] = __builtin_amdgcn_mfma_f32_16x16x32_bf16(a, b[bf], ch[mi][bf], 0, 0, 0);
        }
    }
    __syncthreads();   // all reads of old-h in X complete

    // ---- GRU epilogue: wave w writes d-range [32w,32w+32) for all 64 nodes ----
#pragma unroll
    for (int mi = 0; mi < 2; mi++) {
        int d0 = w * 32 + mi * 16 + krow * 4;
        float4 bsr = *(const float4*)(bsum + d0);
        float4 bsz = *(const float4*)(bsum + 128 + d0);
        float4 bsn = *(const float4*)(bsum + 256 + d0);
        float4 vbr = *(const float4*)(vb3 + d0);
        float4 vbz = *(const float4*)(vb3 + 128 + d0);
        float4 vbn = *(const float4*)(vb3 + 256 + d0);
        float4 bhn = *(const float4*)(b_hh + 256 + d0);
        float bsrv[4] = {bsr.x, bsr.y, bsr.z, bsr.w};
        float bszv[4] = {bsz.x, bsz.y, bsz.z, bsz.w};
        float bsnv[4] = {bsn.x, bsn.y, bsn.z, bsn.w};
        float vbrv[4] = {vbr.x, vbr.y, vbr.z, vbr.w};
        float vbzv[4] = {vbz.x, vbz.y, vbz.z, vbz.w};
        float vbnv[4] = {vbn.x, vbn.y, vbn.z, vbn.w};
        float bhnv[4] = {bhn.x, bhn.y, bhn.z, bhn.w};
#pragma unroll
        for (int bf = 0; bf < 4; bf++) {
            int n = nb + bf * 16 + col;
            bool valid = (n < N_NODES);
            float deg = degs[bf * 16 + col];
            float4 ho = make_float4(0.f, 0.f, 0.f, 0.f);
            if (valid) ho = *(const float4*)(h + (size_t)n * 128 + d0);
            float hov[4] = {ho.x, ho.y, ho.z, ho.w};
            float hv[4];
#pragma unroll
            for (int r = 0; r < 4; r++) {
                float rp = cg[mi][bf][r]     + bsrv[r] + deg * vbrv[r];
                float zp = cg[2 + mi][bf][r] + bszv[r] + deg * vbzv[r];
                float ip = ci[mi][bf][r]     + bsnv[r] + deg * vbnv[r];
                float hp = ch[mi][bf][r]     + bhnv[r];
                float rg = 1.f / (1.f + __expf(-rp));
                float zg = 1.f / (1.f + __expf(-zp));
                float ng = fast_tanh(ip + rg * hp);
                hv[r] = (1.f - zg) * ng + zg * hov[r];
            }
            if (valid)
                *(float4*)(h + (size_t)n * 128 + d0) = make_float4(hv[0], hv[1], hv[2], hv[3]);
            *(unsigned int*)(&X[bf][col][160 + d0])     = cvt_pk_bf16(hv[0], hv[1]);
            *(unsigned int*)(&X[bf][col][160 + d0 + 2]) = cvt_pk_bf16(hv[2], hv[3]);
        }
    }
    __syncthreads();   // h_new complete in X

    // ---- out projection: wave w computes rows [16w,16w+16) ----
    f32x4 co[4] = {};
#pragma unroll
    for (int kt = 0; kt < 4; kt++) {
        short8 a = WoutA[(w * 4 + kt) * 64 + l];
#pragma unroll
        for (int bf = 0; bf < 4; bf++) {
            short8 b = *(const short8*)(&X[bf][col][160 + kt * 32 + krow * 8]);
            co[bf] = __builtin_amdgcn_mfma_f32_16x16x32_bf16(a, b, co[bf], 0, 0, 0);
        }
    }
    {
        int o0 = w * 16 + krow * 4;
        float4 bo = *(const float4*)(b_out + o0);
#pragma unroll
        for (int bf = 0; bf < 4; bf++) {
            int n = nb + bf * 16 + col;
            if (n < N_NODES) {
                float* op = out + (size_t)iter * N_NODES * 64 + (size_t)n * 64 + o0;
                *(float4*)op = make_float4(co[bf][0] + bo.x, co[bf][1] + bo.y,
                                           co[bf][2] + bo.z, co[bf][3] + bo.w);
            }
        }
    }

    // ---- hbf writeback ----
    for (int idx = t; idx < 64 * 16; idx += 256) {
        int i = idx >> 4, c = idx & 15;
        int n2 = nb + i;
        if (n2 < N_NODES)
            ((uint4*)(hbf + (size_t)n2 * 128))[c] = *(const uint4*)(&X[i >> 4][i & 15][160 + c * 8]);
    }
}

// ---------------------------------------------------------------------------
extern "C" void kernel_launch(void* const* d_in, const int* in_sizes, int n_in,
                              void* d_out, int out_size, void* d_ws, size_t ws_size,
                              hipStream_t stream)
{
    const float* inp   = (const float*)d_in[0];
    const int*   src   = (const int*)d_in[1];
    const int*   dst   = (const int*)d_in[2];
    const float* W1    = (const float*)d_in[3];
    const float* b1    = (const float*)d_in[4];
    const float* W2    = (const float*)d_in[5];
    const float* b2    = (const float*)d_in[6];
    const float* W3    = (const float*)d_in[7];
    const float* b3    = (const float*)d_in[8];
    const float* W_ih  = (const float*)d_in[9];
    const float* W_hh  = (const float*)d_in[10];
    const float* b_ih  = (const float*)d_in[11];
    const float* b_hh  = (const float*)d_in[12];
    const float* W_out = (const float*)d_in[13];
    const float* b_out = (const float*)d_in[14];
    float* out = (float*)d_out;

    char* ws = (char*)d_ws;
    size_t off = 0;
    auto alloc = [&](size_t bytes) -> void* {
        void* p = ws + off;
        off += (bytes + 255) & ~(size_t)255;
        return p;
    };
    float* h       = (float*)alloc((size_t)N_NODES * 128 * 4);
    unsigned short* hbf = (unsigned short*)alloc((size_t)N_NODES * 128 * 2);
    float* r2agg   = (float*)alloc((size_t)NPAD * 96 * 4);
    float* Wbig    = (float*)alloc((size_t)256 * 288 * 4);
    float* Wni     = (float*)alloc((size_t)128 * 160 * 4);
    float* vb3     = (float*)alloc((size_t)384 * 4);
    float* bsum    = (float*)alloc((size_t)384 * 4);
    unsigned short* W1A   = (unsigned short*)alloc((size_t)6 * 8 * 512 * 2);
    unsigned short* W2A   = (unsigned short*)alloc((size_t)6 * 3 * 512 * 2);
    unsigned short* WbigA = (unsigned short*)alloc((size_t)16 * 9 * 512 * 2);
    unsigned short* WniA  = (unsigned short*)alloc((size_t)8 * 5 * 512 * 2);
    unsigned short* WnhA  = (unsigned short*)alloc((size_t)8 * 4 * 512 * 2);
    unsigned short* WoutA = (unsigned short*)alloc((size_t)4 * 4 * 512 * 2);
    int*   counts  = (int*)alloc((size_t)N_NODES * 4);
    int*   cursor  = (int*)alloc((size_t)N_NODES * 4);
    int*   row_off = (int*)alloc((size_t)(N_NODES + 1) * 4);
    int*   perm_src= (int*)alloc((size_t)N_EDGES * 4);
    int*   perm_dst= (int*)alloc((size_t)N_EDGES * 4);

    // ---- one-time preprocessing ----
    hipMemsetAsync(h, 0, (size_t)N_NODES * 128 * 4, stream);
    hipMemsetAsync(hbf, 0, (size_t)N_NODES * 128 * 2, stream);
    hipMemsetAsync(counts, 0, (size_t)N_NODES * 4, stream);
    hipMemsetAsync(cursor, 0, (size_t)N_NODES * 4, stream);

    k_build_wbig<<<(256 * 288 + 255) / 256, 256, 0, stream>>>(W_ih, W3, W_hh, Wbig);
    k_build_wni<<<(128 * 160 + 255) / 256, 256, 0, stream>>>(W_ih, W3, Wni);
    k_vb3<<<2, 256, 0, stream>>>(W_ih, b3, vb3);
    k_bsum<<<2, 256, 0, stream>>>(b_ih, b_hh, bsum);

    k_pack2<<<(6 * 8 * 512 + 255) / 256, 256, 0, stream>>>(W1, W1A, 6, 8, 256, 0);
    k_pack2<<<(6 * 3 * 512 + 255) / 256, 256, 0, stream>>>(W2, W2A, 6, 3, 96, 0);
    k_pack2<<<(16 * 9 * 512 + 255) / 256, 256, 0, stream>>>(Wbig, WbigA, 16, 9, 288, 0);
    k_pack2<<<(8 * 5 * 512 + 255) / 256, 256, 0, stream>>>(Wni, WniA, 8, 5, 160, 0);
    k_pack2<<<(8 * 4 * 512 + 255) / 256, 256, 0, stream>>>(W_hh, WnhA, 8, 4, 128, 256);
    k_pack2<<<(4 * 4 * 512 + 255) / 256, 256, 0, stream>>>(W_out, WoutA, 4, 4, 128, 0);

    k_hist<<<(N_EDGES + 255) / 256, 256, 0, stream>>>(dst, counts);
    k_scan<<<1, 1024, 0, stream>>>(counts, row_off);
    k_permute<<<(N_EDGES + 255) / 256, 256, 0, stream>>>(src, dst, row_off, cursor,
                                                         perm_src, perm_dst);

    // ---- iterations ----
    for (int it = 0; it < N_ITERS; ++it) {
        hipMemsetAsync(r2agg, 0, (size_t)NPAD * 96 * 4, stream);
        k_edge_fused<<<512, 256, 0, stream>>>(hbf, perm_src, perm_dst,
                                              (const short8*)W1A, (const short8*)W2A,
                                              b1, b2, r2agg);
        k_node_mfma<<<(N_NODES + 63) / 64, 256, 0, stream>>>(inp, r2agg, row_off, h, hbf,
                                                     (const short8*)WbigA, (const short8*)WniA,
                                                     (const short8*)WnhA, (const short8*)WoutA,
                                                     vb3, bsum, b_hh, b_out, out, it);
    }
}

// Round 19
// 1581.453 us; speedup vs baseline: 2.2368x; 1.0495x over previous
//
#include <hip/hip_runtime.h>

#define N_NODES 50000
#define N_EDGES 800000
#define N_ITERS 7
#define NPAD 50048
#define NT16 (N_EDGES / 16)   // 50000 16-edge tiles
#define TOTP 1024             // 512 blocks x 2 pairs
#define TPP ((NT16 + TOTP - 1) / TOTP)   // 49 tiles per pair

typedef __attribute__((ext_vector_type(8))) short short8;
typedef __attribute__((ext_vector_type(4))) float f32x4;

#define AROW 104   // pair-shared relay row: 96 bf16 + 8 pad
#define XROW 296   // X row: 288 bf16 + 8 pad

static __device__ __forceinline__ unsigned short f2bf(float f) {
    unsigned int u = __float_as_uint(f);
    unsigned int r = (u + 0x7fffu + ((u >> 16) & 1u)) >> 16;
    return (unsigned short)r;
}
static __device__ __forceinline__ float bf2f(unsigned short u) {
    return __uint_as_float(((unsigned int)u) << 16);
}
// pack two f32 -> 2x bf16 (RNE), lo in bits [15:0]
static __device__ __forceinline__ unsigned cvt_pk_bf16(float lo, float hi) {
    unsigned r;
    asm("v_cvt_pk_bf16_f32 %0, %1, %2" : "=v"(r) : "v"(lo), "v"(hi));
    return r;
}
static __device__ __forceinline__ float fast_tanh(float x) {
    float xc = fminf(fmaxf(x, -15.f), 15.f);
    float t = __expf(2.f * xc);
    return (t - 1.f) / (t + 1.f);
}
// row_ror:1 (0x121): lane i <- lane (i-1) mod 16, so col0 receives col15.
static __device__ __forceinline__ float ror_prev(float x) {
    return __int_as_float(__builtin_amdgcn_update_dpp(0, __float_as_int(x), 0x121, 0xf, 0xf, true));
}

// one segmented-scan step over the 16-lane row group (row_shr:CTRL&15, bound_ctrl=1)
template <int CTRL, int N>
static __device__ __forceinline__ void seg_step(float (&s)[N], unsigned& fl) {
    unsigned fv = (unsigned)__builtin_amdgcn_update_dpp(0, (int)fl, CTRL, 0xf, 0xf, true);
    float g = fl ? 0.f : 1.f;
#pragma unroll
    for (int q = 0; q < N; q++) {
        int sv = __builtin_amdgcn_update_dpp(0, __float_as_int(s[q]), CTRL, 0xf, 0xf, true);
        s[q] += __int_as_float(sv) * g;
    }
    fl |= fv;
}

// ---------------------------------------------------------------------------
// Wbig [256][288]: rows = r,z gates; cols = [W_ih[:, :64] | W_ih[:,64:]@W3 | W_hh]
__global__ __launch_bounds__(256) void k_build_wbig(const float* __restrict__ W_ih,
                                                    const float* __restrict__ W3,
                                                    const float* __restrict__ W_hh,
                                                    float* __restrict__ Wbig) {
    int idx = blockIdx.x * 256 + threadIdx.x;
    if (idx >= 256 * 288) return;
    int g = idx / 288, k = idx - g * 288;
    float v;
    if (k < 64) v = W_ih[g * 192 + k];
    else if (k < 160) {
        int kk = k - 64; float s = 0.f;
        for (int j = 0; j < 128; j++) s += W_ih[g * 192 + 64 + j] * W3[j * 96 + kk];
        v = s;
    } else v = W_hh[g * 128 + (k - 160)];
    Wbig[idx] = v;
}

// Wni [128][160]: n-gate input part (W_ih rows 256..383, with W3 fold)
__global__ __launch_bounds__(256) void k_build_wni(const float* __restrict__ W_ih,
                                                   const float* __restrict__ W3,
                                                   float* __restrict__ Wni) {
    int idx = blockIdx.x * 256 + threadIdx.x;
    if (idx >= 128 * 160) return;
    int g = idx / 160, k = idx - g * 160;
    int gg = 256 + g;
    float v;
    if (k < 64) v = W_ih[gg * 192 + k];
    else {
        int kk = k - 64; float s = 0.f;
        for (int j = 0; j < 128; j++) s += W_ih[gg * 192 + 64 + j] * W3[j * 96 + kk];
        v = s;
    }
    Wni[idx] = v;
}

__global__ __launch_bounds__(256) void k_vb3(const float* __restrict__ W_ih,
                                             const float* __restrict__ b3,
                                             float* __restrict__ vb3) {
    int g = blockIdx.x * 256 + threadIdx.x;
    if (g >= 384) return;
    float s = 0.f;
    for (int j = 0; j < 128; j++) s += W_ih[g * 192 + 64 + j] * b3[j];
    vb3[g] = s;
}

__global__ __launch_bounds__(256) void k_bsum(const float* __restrict__ b_ih,
                                              const float* __restrict__ b_hh,
                                              float* __restrict__ bsum) {
    int d = blockIdx.x * 256 + threadIdx.x;
    if (d >= 384) return;
    bsum[d] = b_ih[d] + (d < 256 ? b_hh[d] : 0.f);
}

// ---------------------------------------------------------------------------
// Pack: src fp32 (ld), element (row0+j, k) -> A-frags [Mt][KT][64][8]
__global__ __launch_bounds__(256) void k_pack2(const float* __restrict__ src,
                                               unsigned short* __restrict__ out,
                                               int Mt, int KT, int ld, int row0) {
    int idx = blockIdx.x * 256 + threadIdx.x;
    if (idx >= Mt * KT * 512) return;
    int jj = idx & 7;
    int l  = (idx >> 3) & 63;
    int tile = idx >> 9;
    int kt = tile % KT;
    int mt = tile / KT;
    int j = row0 + mt * 16 + (l & 15);
    int k = kt * 32 + (l >> 4) * 8 + jj;
    out[idx] = f2bf(src[(size_t)j * ld + k]);
}

// ---------------------------------------------------------------------------
// CSR build (once; ids fixed across iterations)
__global__ __launch_bounds__(256) void k_hist(const int* __restrict__ dst,
                                              int* __restrict__ counts) {
    int e = blockIdx.x * 256 + threadIdx.x;
    if (e < N_EDGES) atomicAdd(&counts[dst[e]], 1);
}

__global__ __launch_bounds__(1024) void k_scan(const int* __restrict__ counts,
                                               int* __restrict__ row_off) {
    __shared__ int sh[1024];
    int t = threadIdx.x;
    const int STR = 49;
    int base = t * STR;
    int s = 0;
    for (int i = 0; i < STR; i++) {
        int n = base + i;
        if (n < N_NODES) s += counts[n];
    }
    sh[t] = s;
    __syncthreads();
    for (int off = 1; off < 1024; off <<= 1) {
        int v = (t >= off) ? sh[t - off] : 0;
        __syncthreads();
        sh[t] += v;
        __syncthreads();
    }
    int run = (t == 0) ? 0 : sh[t - 1];
    for (int i = 0; i < STR; i++) {
        int n = base + i;
        if (n < N_NODES) { row_off[n] = run; run += counts[n]; }
    }
    if (t == 1023) row_off[N_NODES] = run;
}

__global__ __launch_bounds__(256) void k_permute(const int* __restrict__ src,
                                                 const int* __restrict__ dst,
                                                 const int* __restrict__ row_off,
                                                 int* __restrict__ cursor,
                                                 int* __restrict__ perm_src,
                                                 int* __restrict__ perm_dst) {
    int e = blockIdx.x * 256 + threadIdx.x;
    if (e >= N_EDGES) return;
    int d = dst[e];
    int pos = row_off[d] + atomicAdd(&cursor[d], 1);
    perm_src[pos] = src[e];
    perm_dst[pos] = d;
}

// ---------------------------------------------------------------------------
// Fused edge MLP + aggregation, SPLIT-M wave pairs (88 VGPR @ 22% occ, R17/18).
// R19: (a) relay double-buffered -> ONE barrier per tile (happens-before via
// the pre-L2 barrier of tile t+1); (b) frag prefetch for t+1 issued right
// after L1 consumes frS/frD (cover = epilogue+barrier+L2+scan, ~2x R18);
// (c) ids prefetched 2 tiles ahead so prefetch addresses are never
// load-dependent. LDS 80896 <= 81920 proven 2-blocks/CU at VGPR<=128 (R5).
__global__ __launch_bounds__(256) void k_edge_fused(
    const unsigned short* __restrict__ hbf,   // [N][128] bf16
    const int* __restrict__ perm_src, const int* __restrict__ perm_dst,
    const short8* __restrict__ W1Ag,          // [6*8*64] frags
    const short8* __restrict__ W2Ag,          // [6*3*64] frags
    const float* __restrict__ b1,
    const float* __restrict__ b2,
    float* __restrict__ r2agg)                // [NPAD][96]
{
    __shared__ __attribute__((aligned(16))) short8 W1s[6 * 8 * 64];      // 49152 B
    __shared__ __attribute__((aligned(16))) short8 W2s[6 * 3 * 64];      // 18432 B
    __shared__ __attribute__((aligned(16))) unsigned short relay[2][2][16][AROW]; // 13312 B

    int t = threadIdx.x;
    int w = t >> 6, l = t & 63;
    int col = l & 15, krow = l >> 4;
    int pair = w >> 1;          // 0..1
    int u = w & 1;              // M-half: neurons [48u, 48u+48)
    int mtb = 3 * u;            // global mt base

    for (int i = t; i < 6 * 8 * 64; i += 256) W1s[i] = W1Ag[i];
    for (int i = t; i < 6 * 3 * 64; i += 256) W2s[i] = W2Ag[i];
    __syncthreads();

    int pidx = blockIdx.x * 2 + pair;
    int tlo = pidx * TPP;
    int thi = tlo + TPP; if (thi > NT16) thi = NT16;
    int ntiles = thi - tlo; if (ntiles < 0) ntiles = 0;

    float carry[12];
#pragma unroll
    for (int q = 0; q < 12; q++) carry[q] = 0.f;
    bool head = true;

    // ---- id pipeline: tiles t (0), t+1 (1); frag buffers hold tile t ----
    auto ldids = [&](int tile, int& s_, int& d_) {
        int te = tile; if (te >= NT16) te = NT16 - 1; if (te < 0) te = 0;
        int e = te * 16 + col; s_ = perm_src[e]; d_ = perm_dst[e];
    };
    int sid0, did0, sid1, did1, sid2, did2;
    ldids(tlo, sid0, did0);
    ldids(tlo + 1, sid1, did1);
    short8 frS[4], frD[4];
    {
        const unsigned short* sr = hbf + (size_t)sid0 * 128 + krow * 8;
        const unsigned short* dr = hbf + (size_t)did0 * 128 + krow * 8;
#pragma unroll
        for (int kt = 0; kt < 4; kt++) frS[kt] = *(const short8*)(sr + kt * 32);
#pragma unroll
        for (int kt = 0; kt < 4; kt++) frD[kt] = *(const short8*)(dr + kt * 32);
    }

    for (int tt = 0; tt < TPP; ++tt) {
        bool active = (tt < ntiles);
        bool hasN = (tt + 1 < ntiles);
        int buf = tt & 1;

        // issue ids for tile tt+2 (cover: whole tile)
        ldids(tlo + tt + 2, sid2, did2);

        int dp = __shfl_up(did0, 1);
        unsigned m16 = (unsigned)__ballot((col == 0) || (did0 != dp)) & 0xFFFFu;
        bool continuing = hasN && (__shfl(did0, 15) == __shfl(did1, 0));

        // ---- L1: 3 mt x 8 kt, both halves in registers ----
        f32x4 c1[3] = {};
        __builtin_amdgcn_s_setprio(1);
#pragma unroll
        for (int kt = 0; kt < 4; kt++) {
#pragma unroll
            for (int mt = 0; mt < 3; mt++)
                c1[mt] = __builtin_amdgcn_mfma_f32_16x16x32_bf16(W1s[((mtb + mt) * 8 + kt) * 64 + l], frS[kt], c1[mt], 0, 0, 0);
        }
#pragma unroll
        for (int kt = 0; kt < 4; kt++) {
#pragma unroll
            for (int mt = 0; mt < 3; mt++)
                c1[mt] = __builtin_amdgcn_mfma_f32_16x16x32_bf16(W1s[((mtb + mt) * 8 + 4 + kt) * 64 + l], frD[kt], c1[mt], 0, 0, 0);
        }
        __builtin_amdgcn_s_setprio(0);

        // ---- prefetch BOTH halves of tile tt+1 immediately (max cover) ----
        {
            const unsigned short* sr = hbf + (size_t)sid1 * 128 + krow * 8;
            const unsigned short* dr = hbf + (size_t)did1 * 128 + krow * 8;
#pragma unroll
            for (int kt = 0; kt < 4; kt++) frS[kt] = *(const short8*)(sr + kt * 32);
#pragma unroll
            for (int kt = 0; kt < 4; kt++) frD[kt] = *(const short8*)(dr + kt * 32);
        }

        // ---- a1 epilogue: wave writes its 48 dims of relay[buf][pair] ----
#pragma unroll
        for (int mt = 0; mt < 3; mt++) {
#pragma unroll
            for (int r = 0; r < 4; r += 2) {
                int j0 = (mtb + mt) * 16 + krow * 4 + r;
                float v0 = fmaxf(c1[mt][r]     + b1[j0],     0.f);
                float v1 = fmaxf(c1[mt][r + 1] + b1[j0 + 1], 0.f);
                *(unsigned int*)(&relay[buf][pair][col][j0]) = cvt_pk_bf16(v0, v1);
            }
        }
        __syncthreads();   // ONLY barrier: both halves of relay[buf] complete

        // ---- L2: full-K read, own 3 mt ----
        f32x4 c2[3] = {};
        __builtin_amdgcn_s_setprio(1);
#pragma unroll
        for (int kt = 0; kt < 3; kt++) {
            short8 b = *(const short8*)(&relay[buf][pair][col][kt * 32 + krow * 8]);
#pragma unroll
            for (int mt = 0; mt < 3; mt++)
                c2[mt] = __builtin_amdgcn_mfma_f32_16x16x32_bf16(W2s[((mtb + mt) * 3 + kt) * 64 + l], b, c2[mt], 0, 0, 0);
        }
        __builtin_amdgcn_s_setprio(0);

        // ---- msg (bias+relu); inject carry at col0 ----
        float s[12];
#pragma unroll
        for (int mt = 0; mt < 3; mt++)
#pragma unroll
            for (int r = 0; r < 4; r++) {
                int j = (mtb + mt) * 16 + krow * 4 + r;
                float v = fmaxf(c2[mt][r] + b2[j], 0.f);
                s[mt * 4 + r] = v + ((col == 0) ? carry[mt * 4 + r] : 0.f);
            }
        // ---- segmented inclusive scan over col ----
        unsigned fl = (m16 >> col) & 1u;
        seg_step<0x111>(s, fl);
        seg_step<0x112>(s, fl);
        seg_step<0x114>(s, fl);
        seg_step<0x118>(s, fl);
        // ---- emission (wave's 48 dims only) ----
        bool is_end = (col == 15) || ((m16 >> (col + 1)) & 1u);
        if (active && is_end && !((col == 15) && continuing)) {
            unsigned lowmask = (2u << col) - 1u;
            bool first_seg = (__popc(m16 & lowmask) == 1);
            bool use_atomic = (first_seg && head) || ((col == 15) && !hasN);
            float* base = r2agg + (size_t)did0 * 96 + krow * 4;
            if (use_atomic) {
#pragma unroll
                for (int mt = 0; mt < 3; mt++)
#pragma unroll
                    for (int r = 0; r < 4; r++)
                        atomicAdd(base + (mtb + mt) * 16 + r, s[mt * 4 + r]);
            } else {
#pragma unroll
                for (int mt = 0; mt < 3; mt++)
                    *(float4*)(base + (mtb + mt) * 16) = make_float4(s[mt * 4], s[mt * 4 + 1],
                                                                    s[mt * 4 + 2], s[mt * 4 + 3]);
            }
        }
        // ---- carry update (wave-uniform) ----
        if (continuing) {
            head = head && (m16 == 1u);
#pragma unroll
            for (int q = 0; q < 12; q++) carry[q] = ror_prev(s[q]);
        } else {
            head = false;
#pragma unroll
            for (int q = 0; q < 12; q++) carry[q] = 0.f;
        }
        sid0 = sid1; did0 = did1;
        sid1 = sid2; did1 = did2;
    }
}

// ---------------------------------------------------------------------------
// Node phase: 4 waves x 64 shared nodes; wave w owns d-range [32w,32w+32)
// of all gates (and out rows [16w,16w+16)). Weights read once per wave with
// x4 B-frag reuse. 3 barriers, no weight staging.
__global__ __launch_bounds__(256) void k_node_mfma(
    const float* __restrict__ inp,      // [N][64]
    const float* __restrict__ r2agg,    // [NPAD][96]
    const int* __restrict__ row_off,    // [N+1]
    float* __restrict__ h,              // [N][128] fp32 in/out
    unsigned short* __restrict__ hbf,   // [N][128] bf16 in/out
    const short8* __restrict__ WbigA,   // [16][9] tiles
    const short8* __restrict__ WniA,    // [8][5]
    const short8* __restrict__ WnhA,    // [8][4]
    const short8* __restrict__ WoutA,   // [4][4]
    const float* __restrict__ vb3,
    const float* __restrict__ bsum,
    const float* __restrict__ b_hh,
    const float* __restrict__ b_out,
    float* __restrict__ out, int iter)
{
    __shared__ __attribute__((aligned(16))) unsigned short X[4][16][XROW]; // 37888 B
    __shared__ float degs[64];
    int t = threadIdx.x;
    int w = t >> 6, l = t & 63;
    int nb = blockIdx.x * 64;
    int col = l & 15, krow = l >> 4;

    // ---- stage X = [inp(64) | r2(96) | h(128)] bf16 + degs ----
    for (int idx = t; idx < 64 * 32; idx += 256) {
        int i = idx >> 5, kk = (idx & 31) << 1;
        int n = nb + i;
        float2 v = make_float2(0.f, 0.f);
        if (n < N_NODES) v = *(const float2*)(inp + (size_t)n * 64 + kk);
        *(unsigned int*)(&X[i >> 4][i & 15][kk]) = cvt_pk_bf16(v.x, v.y);
    }
    for (int idx = t; idx < 64 * 48; idx += 256) {      // r2 node-major pairs
        int i = (int)((unsigned)idx / 48u), kp = idx - i * 48;
        int n = nb + i;
        float2 v = make_float2(0.f, 0.f);
        if (n < N_NODES) v = *(const float2*)(r2agg + (size_t)n * 96 + kp * 2);
        *(unsigned int*)(&X[i >> 4][i & 15][64 + kp * 2]) = cvt_pk_bf16(v.x, v.y);
    }
    for (int idx = t; idx < 64 * 16; idx += 256) {
        int i = idx >> 4, c = idx & 15;
        int n = nb + i;
        uint4 v = make_uint4(0, 0, 0, 0);
        if (n < N_NODES) v = ((const uint4*)(hbf + (size_t)n * 128))[c];
        *(uint4*)(&X[i >> 4][i & 15][160 + c * 8]) = v;
    }
    if (t < 64) {
        int n = nb + t;
        degs[t] = (n < N_NODES) ? (float)(row_off[n + 1] - row_off[n]) : 0.f;
    }
    __syncthreads();

    // ---- GEMMs: wave w computes d in [32w, 32w+32) ----
    int mts[4] = {2 * w, 2 * w + 1, 8 + 2 * w, 9 + 2 * w};   // r lo/hi, z lo/hi
    f32x4 cg[4][4] = {};
#pragma unroll 3
    for (int kt = 0; kt < 9; kt++) {
        short8 b[4];
#pragma unroll
        for (int bf = 0; bf < 4; bf++) b[bf] = *(const short8*)(&X[bf][col][kt * 32 + krow * 8]);
#pragma unroll
        for (int mi = 0; mi < 4; mi++) {
            short8 a = WbigA[(mts[mi] * 9 + kt) * 64 + l];
#pragma unroll
            for (int bf = 0; bf < 4; bf++)
                cg[mi][bf] = __builtin_amdgcn_mfma_f32_16x16x32_bf16(a, b[bf], cg[mi][bf], 0, 0, 0);
        }
    }
    f32x4 ci[2][4] = {};
#pragma unroll
    for (int kt = 0; kt < 5; kt++) {
        short8 b[4];
#pragma unroll
        for (int bf = 0; bf < 4; bf++) b[bf] = *(const short8*)(&X[bf][col][kt * 32 + krow * 8]);
#pragma unroll
        for (int mi = 0; mi < 2; mi++) {
            short8 a = WniA[((2 * w + mi) * 5 + kt) * 64 + l];
#pragma unroll
            for (int bf = 0; bf < 4; bf++)
                ci[mi][bf] = __builtin_amdgcn_mfma_f32_16x16x32_bf16(a, b[bf], ci[mi][bf], 0, 0, 0);
        }
    }
    f32x4 ch[2][4] = {};
#pragma unroll
    for (int kt = 0; kt < 4; kt++) {
        short8 b[4];
#pragma unroll
        for (int bf = 0; bf < 4; bf++) b[bf] = *(const short8*)(&X[bf][col][160 + kt * 32 + krow * 8]);
#pragma unroll
        for (int mi = 0; mi < 2; mi++) {
            short8 a = WnhA[((2 * w + mi) * 4 + kt) * 64 + l];
#pragma unroll
            for (int bf = 0; bf < 4; bf++)
                ch[mi][bf] = __builtin_amdgcn_mfma_f32_16x16x32_bf16(a, b[bf], ch[mi][bf], 0, 0, 0);
        }
    }
    __syncthreads();   // all reads of old-h in X complete

    // ---- GRU epilogue: wave w writes d-range [32w,32w+32) for all 64 nodes ----
#pragma unroll
    for (int mi = 0; mi < 2; mi++) {
        int d0 = w * 32 + mi * 16 + krow * 4;
        float4 bsr = *(const float4*)(bsum + d0);
        float4 bsz = *(const float4*)(bsum + 128 + d0);
        float4 bsn = *(const float4*)(bsum + 256 + d0);
        float4 vbr = *(const float4*)(vb3 + d0);
        float4 vbz = *(const float4*)(vb3 + 128 + d0);
        float4 vbn = *(const float4*)(vb3 + 256 + d0);
        float4 bhn = *(const float4*)(b_hh + 256 + d0);
        float bsrv[4] = {bsr.x, bsr.y, bsr.z, bsr.w};
        float bszv[4] = {bsz.x, bsz.y, bsz.z, bsz.w};
        float bsnv[4] = {bsn.x, bsn.y, bsn.z, bsn.w};
        float vbrv[4] = {vbr.x, vbr.y, vbr.z, vbr.w};
        float vbzv[4] = {vbz.x, vbz.y, vbz.z, vbz.w};
        float vbnv[4] = {vbn.x, vbn.y, vbn.z, vbn.w};
        float bhnv[4] = {bhn.x, bhn.y, bhn.z, bhn.w};
#pragma unroll
        for (int bf = 0; bf < 4; bf++) {
            int n = nb + bf * 16 + col;
            bool valid = (n < N_NODES);
            float deg = degs[bf * 16 + col];
            float4 ho = make_float4(0.f, 0.f, 0.f, 0.f);
            if (valid) ho = *(const float4*)(h + (size_t)n * 128 + d0);
            float hov[4] = {ho.x, ho.y, ho.z, ho.w};
            float hv[4];
#pragma unroll
            for (int r = 0; r < 4; r++) {
                float rp = cg[mi][bf][r]     + bsrv[r] + deg * vbrv[r];
                float zp = cg[2 + mi][bf][r] + bszv[r] + deg * vbzv[r];
                float ip = ci[mi][bf][r]     + bsnv[r] + deg * vbnv[r];
                float hp = ch[mi][bf][r]     + bhnv[r];
                float rg = 1.f / (1.f + __expf(-rp));
                float zg = 1.f / (1.f + __expf(-zp));
                float ng = fast_tanh(ip + rg * hp);
                hv[r] = (1.f - zg) * ng + zg * hov[r];
            }
            if (valid)
                *(float4*)(h + (size_t)n * 128 + d0) = make_float4(hv[0], hv[1], hv[2], hv[3]);
            *(unsigned int*)(&X[bf][col][160 + d0])     = cvt_pk_bf16(hv[0], hv[1]);
            *(unsigned int*)(&X[bf][col][160 + d0 + 2]) = cvt_pk_bf16(hv[2], hv[3]);
        }
    }
    __syncthreads();   // h_new complete in X

    // ---- out projection: wave w computes rows [16w,16w+16) ----
    f32x4 co[4] = {};
#pragma unroll
    for (int kt = 0; kt < 4; kt++) {
        short8 a = WoutA[(w * 4 + kt) * 64 + l];
#pragma unroll
        for (int bf = 0; bf < 4; bf++) {
            short8 b = *(const short8*)(&X[bf][col][160 + kt * 32 + krow * 8]);
            co[bf] = __builtin_amdgcn_mfma_f32_16x16x32_bf16(a, b, co[bf], 0, 0, 0);
        }
    }
    {
        int o0 = w * 16 + krow * 4;
        float4 bo = *(const float4*)(b_out + o0);
#pragma unroll
        for (int bf = 0; bf < 4; bf++) {
            int n = nb + bf * 16 + col;
            if (n < N_NODES) {
                float* op = out + (size_t)iter * N_NODES * 64 + (size_t)n * 64 + o0;
                *(float4*)op = make_float4(co[bf][0] + bo.x, co[bf][1] + bo.y,
                                           co[bf][2] + bo.z, co[bf][3] + bo.w);
            }
        }
    }

    // ---- hbf writeback ----
    for (int idx = t; idx < 64 * 16; idx += 256) {
        int i = idx >> 4, c = idx & 15;
        int n2 = nb + i;
        if (n2 < N_NODES)
            ((uint4*)(hbf + (size_t)n2 * 128))[c] = *(const uint4*)(&X[i >> 4][i & 15][160 + c * 8]);
    }
}

// ---------------------------------------------------------------------------
extern "C" void kernel_launch(void* const* d_in, const int* in_sizes, int n_in,
                              void* d_out, int out_size, void* d_ws, size_t ws_size,
                              hipStream_t stream)
{
    const float* inp   = (const float*)d_in[0];
    const int*   src   = (const int*)d_in[1];
    const int*   dst   = (const int*)d_in[2];
    const float* W1    = (const float*)d_in[3];
    const float* b1    = (const float*)d_in[4];
    const float* W2    = (const float*)d_in[5];
    const float* b2    = (const float*)d_in[6];
    const float* W3    = (const float*)d_in[7];
    const float* b3    = (const float*)d_in[8];
    const float* W_ih  = (const float*)d_in[9];
    const float* W_hh  = (const float*)d_in[10];
    const float* b_ih  = (const float*)d_in[11];
    const float* b_hh  = (const float*)d_in[12];
    const float* W_out = (const float*)d_in[13];
    const float* b_out = (const float*)d_in[14];
    float* out = (float*)d_out;

    char* ws = (char*)d_ws;
    size_t off = 0;
    auto alloc = [&](size_t bytes) -> void* {
        void* p = ws + off;
        off += (bytes + 255) & ~(size_t)255;
        return p;
    };
    float* h       = (float*)alloc((size_t)N_NODES * 128 * 4);
    unsigned short* hbf = (unsigned short*)alloc((size_t)N_NODES * 128 * 2);
    float* r2agg   = (float*)alloc((size_t)NPAD * 96 * 4);
    float* Wbig    = (float*)alloc((size_t)256 * 288 * 4);
    float* Wni     = (float*)alloc((size_t)128 * 160 * 4);
    float* vb3     = (float*)alloc((size_t)384 * 4);
    float* bsum    = (float*)alloc((size_t)384 * 4);
    unsigned short* W1A   = (unsigned short*)alloc((size_t)6 * 8 * 512 * 2);
    unsigned short* W2A   = (unsigned short*)alloc((size_t)6 * 3 * 512 * 2);
    unsigned short* WbigA = (unsigned short*)alloc((size_t)16 * 9 * 512 * 2);
    unsigned short* WniA  = (unsigned short*)alloc((size_t)8 * 5 * 512 * 2);
    unsigned short* WnhA  = (unsigned short*)alloc((size_t)8 * 4 * 512 * 2);
    unsigned short* WoutA = (unsigned short*)alloc((size_t)4 * 4 * 512 * 2);
    int*   counts  = (int*)alloc((size_t)N_NODES * 4);
    int*   cursor  = (int*)alloc((size_t)N_NODES * 4);
    int*   row_off = (int*)alloc((size_t)(N_NODES + 1) * 4);
    int*   perm_src= (int*)alloc((size_t)N_EDGES * 4);
    int*   perm_dst= (int*)alloc((size_t)N_EDGES * 4);

    // ---- one-time preprocessing ----
    hipMemsetAsync(h, 0, (size_t)N_NODES * 128 * 4, stream);
    hipMemsetAsync(hbf, 0, (size_t)N_NODES * 128 * 2, stream);
    hipMemsetAsync(counts, 0, (size_t)N_NODES * 4, stream);
    hipMemsetAsync(cursor, 0, (size_t)N_NODES * 4, stream);

    k_build_wbig<<<(256 * 288 + 255) / 256, 256, 0, stream>>>(W_ih, W3, W_hh, Wbig);
    k_build_wni<<<(128 * 160 + 255) / 256, 256, 0, stream>>>(W_ih, W3, Wni);
    k_vb3<<<2, 256, 0, stream>>>(W_ih, b3, vb3);
    k_bsum<<<2, 256, 0, stream>>>(b_ih, b_hh, bsum);

    k_pack2<<<(6 * 8 * 512 + 255) / 256, 256, 0, stream>>>(W1, W1A, 6, 8, 256, 0);
    k_pack2<<<(6 * 3 * 512 + 255) / 256, 256, 0, stream>>>(W2, W2A, 6, 3, 96, 0);
    k_pack2<<<(16 * 9 * 512 + 255) / 256, 256, 0, stream>>>(Wbig, WbigA, 16, 9, 288, 0);
    k_pack2<<<(8 * 5 * 512 + 255) / 256, 256, 0, stream>>>(Wni, WniA, 8, 5, 160, 0);
    k_pack2<<<(8 * 4 * 512 + 255) / 256, 256, 0, stream>>>(W_hh, WnhA, 8, 4, 128, 256);
    k_pack2<<<(4 * 4 * 512 + 255) / 256, 256, 0, stream>>>(W_out, WoutA, 4, 4, 128, 0);

    k_hist<<<(N_EDGES + 255) / 256, 256, 0, stream>>>(dst, counts);
    k_scan<<<1, 1024, 0, stream>>>(counts, row_off);
    k_permute<<<(N_EDGES + 255) / 256, 256, 0, stream>>>(src, dst, row_off, cursor,
                                                         perm_src, perm_dst);

    // ---- iterations ----
    for (int it = 0; it < N_ITERS; ++it) {
        hipMemsetAsync(r2agg, 0, (size_t)NPAD * 96 * 4, stream);
        k_edge_fused<<<512, 256, 0, stream>>>(hbf, perm_src, perm_dst,
                                              (const short8*)W1A, (const short8*)W2A,
                                              b1, b2, r2agg);
        k_node_mfma<<<(N_NODES + 63) / 64, 256, 0, stream>>>(inp, r2agg, row_off, h, hbf,
                                                     (const short8*)WbigA, (const short8*)WniA,
                                                     (const short8*)WnhA, (const short8*)WoutA,
                                                     vb3, bsum, b_hh, b_out, out, it);
    }
}